// Round 13
// baseline (108.005 us; speedup 1.0000x reference)
//
#include <hip/hip_runtime.h>

typedef unsigned short u16;
typedef __attribute__((ext_vector_type(8))) short bf16x8;
typedef __attribute__((ext_vector_type(4))) float f32x4;

#define S_LEN 2048
#define MTOT  4096   // B*S
#define LOG2E_DIV8 0.1803368784f   // 0.125 * log2(e)

__device__ inline u16 f2bf(float f) {
  union { float f; unsigned u; } x; x.f = f;
  unsigned r = x.u + 0x7fffu + ((x.u >> 16) & 1u);
  return (u16)(r >> 16);
}
__device__ inline float bf2f(u16 u) {
  union { unsigned u; float f; } x; x.u = ((unsigned)u) << 16;
  return x.f;
}

__device__ __forceinline__ unsigned cvtpk_bf16(float lo, float hi) {
  unsigned r;
  asm("v_cvt_pk_bf16_f32 %0, %1, %2" : "=v"(r) : "v"(lo), "v"(hi));
  return r;
}
__device__ __forceinline__ float fexp2(float x) {
  float r;
  asm("v_exp_f32 %0, %1" : "=v"(r) : "v"(x));
  return r;
}
__device__ __forceinline__ float frcp(float x) {
  float r;
  asm("v_rcp_f32 %0, %1" : "=v"(r) : "v"(x));
  return r;
}

// --- gfx950 permlane swaps (both operands updated) ---
#define SWAP32(a, b) asm("v_permlane32_swap_b32 %0, %1" : "+v"(a), "+v"(b))
#define SWAP16(a, b) asm("v_permlane16_swap_b32 %0, %1" : "+v"(a), "+v"(b))

// sum of x over the 4 row-groups (lane bits 4-5), result in every lane
__device__ __forceinline__ float sum_lg(float x) {
  float a = x, b = x;
  SWAP32(a, b);
  float s = a + b;
  float c = s, d = s;
  SWAP16(c, d);
  return c + d;
}

typedef __attribute__((address_space(1))) const unsigned int gu32;
typedef __attribute__((address_space(3))) unsigned int lu32;
__device__ __forceinline__ void gload_lds16(const void* g, void* l) {
  __builtin_amdgcn_global_load_lds((gu32*)g, (lu32*)l, 16, 0, 0);
}

#define MFMA16(a, b, c) __builtin_amdgcn_mfma_f32_16x16x32_bf16((a), (b), (c), 0, 0, 0)
#define BAR  __builtin_amdgcn_s_barrier()
#define VMC6 asm volatile("s_waitcnt vmcnt(6)" ::: "memory")
#define VMC0 asm volatile("s_waitcnt vmcnt(0)" ::: "memory")

// ---- prep: x cast (blocks 0..4095) + weight transpose/cast (blocks 4096+) ----
__global__ __launch_bounds__(256) void prep(const float* __restrict__ x,
                                            const float* __restrict__ wqkv,
                                            const float* __restrict__ wout,
                                            u16* __restrict__ x_bf,
                                            u16* __restrict__ dqkv,
                                            u16* __restrict__ dwout) {
  __shared__ float tile[64][65];
  int bid = blockIdx.x;
  int t = threadIdx.x;
  if (bid < 4096) {
    int i = (bid * 256 + t) * 4;
    float4 v = *(const float4*)(x + i);
    ushort4 o;
    o.x = f2bf(v.x); o.y = f2bf(v.y); o.z = f2bf(v.z); o.w = f2bf(v.w);
    *(ushort4*)(x_bf + i) = o;
    return;
  }
  int idx = bid - 4096;
  int bx = idx & 63, by = idx >> 6;
  const float* src; u16* dst; int N, n0;
  if (bx < 48) { src = wqkv; dst = dqkv; N = 3072; n0 = bx * 64; }
  else         { src = wout; dst = dwout; N = 1024; n0 = (bx - 48) * 64; }
  int K = 1024, k0 = by * 64;
  for (int i = 0; i < 16; ++i) {
    int id2 = t + 256 * i;
    int r = id2 >> 6, c = id2 & 63;
    tile[r][c] = src[(size_t)(k0 + r) * N + n0 + c];
  }
  __syncthreads();
  for (int i = 0; i < 16; ++i) {
    int id2 = t + 256 * i;
    int r = id2 >> 6, c = id2 & 63;
    dst[(size_t)(n0 + r) * K + k0 + c] = f2bf(tile[c][r]);
  }
}

// ---- GEMM1 (QKV): 256x256 tile, BK=64, 8 waves, 8-phase counted-vmcnt ------
// qkv[4096][3072] = x_bf @ wqkvT^T + b_qkv.  LDS 128KB (1 block/CU); launch
// bound (512,1) gives the allocator 256 VGPRs (8 waves/CU exactly).  A-frags
// use ONE array (half-0 dies before half-1 loads) to stay under budget.
__global__ __launch_bounds__(512, 1) void gemm_qkv(const u16* __restrict__ A,
                                                   const u16* __restrict__ Bt,
                                                   const float* __restrict__ bias,
                                                   u16* __restrict__ qkv,
                                                   u16* __restrict__ Vt,
                                                   float qscale) {
  __shared__ __align__(16) u16 smem[65536];   // A: [0,32768) ; B: [32768,65536)
  int t = threadIdx.x;
  int w = t >> 6, l = t & 63;
  int wr = w >> 2, wcn = w & 3;       // wave grid 2(M) x 4(N)
  int lr = l & 15, lg = l >> 4;

  int bid = blockIdx.y * 12 + blockIdx.x;
  int orig = (bid & 7) * 24 + (bid >> 3);    // XCD-chunked remap (192 % 8 == 0)
  int bx = orig % 12, by = orig / 12;
  int m0 = by * 256, n0 = bx * 256;

  f32x4 acc[8][4];
#pragma unroll
  for (int i = 0; i < 8; ++i)
#pragma unroll
    for (int j = 0; j < 4; ++j)
      acc[i][j] = f32x4{0.f, 0.f, 0.f, 0.f};

  // staging: thread t covers (row = h*128 + j*64 + (t>>3), chunk t&7),
  // global chunk pre-swizzled by row&7 so LDS[r][c] = G[r][c ^ (r&7)]
  int cg = ((t & 7) ^ ((t >> 3) & 7)) * 8;
  const u16* gAh[2][2];
  const u16* gBh[2][2];
#pragma unroll
  for (int h = 0; h < 2; ++h)
#pragma unroll
    for (int j = 0; j < 2; ++j) {
      gAh[h][j] = A  + (size_t)(m0 + h * 128 + j * 64 + (t >> 3)) * 1024 + cg;
      gBh[h][j] = Bt + (size_t)(n0 + h * 128 + j * 64 + (t >> 3)) * 1024 + cg;
    }

#define STG_A(kt, h) {                                                  \
    u16* d_ = smem + (((kt) & 1) * 2 + (h)) * 8192 + t * 8;             \
    gload_lds16(gAh[h][0] + (size_t)(kt) * 64, d_);                     \
    gload_lds16(gAh[h][1] + (size_t)(kt) * 64, d_ + 4096);              }
#define STG_B(kt, h) {                                                  \
    u16* d_ = smem + 32768 + (((kt) & 1) * 2 + (h)) * 8192 + t * 8;     \
    gload_lds16(gBh[h][0] + (size_t)(kt) * 64, d_);                     \
    gload_lds16(gBh[h][1] + (size_t)(kt) * 64, d_ + 4096);              }

  // fragment read offsets (within the wave's half-tile), swizzle-corrected
  int o0 = lr * 64 + ((lg ^ (lr & 7)) << 3);           // ks=0: chunk lg
  int o1 = lr * 64 + (((4 + lg) ^ (lr & 7)) << 3);     // ks=1: chunk 4+lg
  const u16* bA[2] = { smem + wr * 8192, smem + (2 + wr) * 8192 };
  const u16* bB[2] = { smem + 32768 + (wcn >> 1) * 8192 + (wcn & 1) * 4096,
                       smem + 32768 + (2 + (wcn >> 1)) * 8192 + (wcn & 1) * 4096 };

  bf16x8 AF[4][2], Bf[4][2];
#define LDA(B_, OFF) { const u16* p_ = bA[B_] + (OFF);                  \
    _Pragma("unroll") for (int mi = 0; mi < 4; ++mi) {                  \
      AF[mi][0] = *(const bf16x8*)(p_ + mi * 1024 + o0);                \
      AF[mi][1] = *(const bf16x8*)(p_ + mi * 1024 + o1); } }
#define LDB(B_) { const u16* p_ = bB[B_];                               \
    _Pragma("unroll") for (int ni = 0; ni < 4; ++ni) {                  \
      Bf[ni][0] = *(const bf16x8*)(p_ + ni * 1024 + o0);                \
      Bf[ni][1] = *(const bf16x8*)(p_ + ni * 1024 + o1); } }
#define QUAD(MO, NO) {                                                  \
    __builtin_amdgcn_s_setprio(1);                                      \
    _Pragma("unroll") for (int mi = 0; mi < 4; ++mi)                    \
    _Pragma("unroll") for (int ni = 0; ni < 2; ++ni) {                  \
      acc[MO + mi][NO + ni] = MFMA16(AF[mi][0], Bf[NO + ni][0], acc[MO + mi][NO + ni]); \
      acc[MO + mi][NO + ni] = MFMA16(AF[mi][1], Bf[NO + ni][1], acc[MO + mi][NO + ni]); } \
    __builtin_amdgcn_s_setprio(0); }

  // prologue: K-tile 0 (all 4 halves) + K-tile 1 {Bh0,Bh1,Ah0} (Ah1 at ph0)
  STG_B(0, 0); STG_B(0, 1); STG_A(0, 0); STG_A(0, 1);
  STG_B(1, 0); STG_B(1, 1); STG_A(1, 0);
  VMC6;                       // force K-tile 0 complete; allow K1's 3 in flight
  BAR;

  for (int i = 0; i < 8; ++i) {
    bool s = (i < 7);
    int k0t = 2 * i, k1t = 2 * i + 1;
    // ph0: read A(m0-3)+B(all) of K-tile k0t; stage Ah1(k1t)
    LDA(0, 0); LDB(0);
    STG_A(k1t, 1);
    BAR; QUAD(0, 0); BAR;
    // ph1: stage Bh0(k0t+2)
    if (s) STG_B(k0t + 2, 0);
    BAR; QUAD(0, 2); BAR;
    // ph2: read A(m4-7); stage Bh1(k0t+2)
    LDA(0, 4096);
    if (s) STG_B(k0t + 2, 1);
    BAR; QUAD(4, 0); BAR;
    // ph3: stage Ah0(k0t+2); CHECKPOINT
    if (s) STG_A(k0t + 2, 0);
    if (i == 7) { VMC0; } else { VMC6; }
    BAR; QUAD(4, 2); BAR;
    // ph4: read K-tile k1t (A m0-3 + B); stage Ah1(k0t+2)
    LDA(1, 0); LDB(1);
    if (s) STG_A(k0t + 2, 1);
    BAR; QUAD(0, 0); BAR;
    // ph5: stage Bh0(k1t+2)
    if (s) STG_B(k1t + 2, 0);
    BAR; QUAD(0, 2); BAR;
    // ph6: read A(m4-7); stage Bh1(k1t+2)
    LDA(1, 4096);
    if (s) STG_B(k1t + 2, 1);
    BAR; QUAD(4, 0); BAR;
    // ph7: stage Ah0(k1t+2); CHECKPOINT
    if (s) STG_A(k1t + 2, 0);
    VMC6;
    BAR; QUAD(4, 2); BAR;
  }
#undef STG_A
#undef STG_B
#undef LDA
#undef LDB
#undef QUAD

  if (bx < 8) {
    // Q/K epilogue: bf16 to qkv; Q columns (bx<4) pre-scaled into log2 domain
    float qs = (bx < 4) ? qscale : 1.0f;
#pragma unroll
    for (int mi = 0; mi < 8; ++mi)
#pragma unroll
      for (int ni = 0; ni < 4; ++ni)
#pragma unroll
        for (int rg = 0; rg < 4; ++rg) {
          int row = m0 + wr * 128 + mi * 16 + lg * 4 + rg;
          int col = n0 + wcn * 64 + ni * 16 + lr;
          qkv[(size_t)row * 3072 + col] = f2bf((acc[mi][ni][rg] + bias[col]) * qs);
        }
    return;
  }

  // V epilogue: per 64-col head group, transpose via LDS (stride 272 -> 16B
  // aligned rows), write Vt[bh][d][s] coalesced.
  int b = by >> 3, sbase = (by & 7) * 256;
  u16* Vl = smem;
#pragma unroll 1
  for (int g = 0; g < 4; ++g) {
    __syncthreads();
    if (wcn == g) {
#pragma unroll
      for (int mi = 0; mi < 8; ++mi)
#pragma unroll
        for (int ni = 0; ni < 4; ++ni) {
          int d = ni * 16 + lr;
          int srow = wr * 128 + mi * 16 + lg * 4;
          int col = n0 + g * 64 + d;
          union { u16 u[4]; unsigned long long q; } pk;
#pragma unroll
          for (int rg = 0; rg < 4; ++rg)
            pk.u[rg] = f2bf(acc[mi][ni][rg] + bias[col]);
          *(unsigned long long*)&Vl[d * 272 + srow] = pk.q;
        }
    }
    __syncthreads();
    int hv = (bx - 8) * 4 + g;
    int d = t >> 3, sc = (t & 7) * 32;
    u16* dst = Vt + ((size_t)((b * 16 + hv) * 64 + d)) * 2048 + sbase + sc;
    const u16* src = Vl + d * 272 + sc;
#pragma unroll
    for (int j = 0; j < 4; ++j)
      *(uint4*)(dst + j * 8) = *(const uint4*)(src + j * 8);
  }
}

// ------------- GEMM2: 64x128 tile, 4 waves of 64x32, 2-phase dbuf -----------
__global__ __launch_bounds__(256) void gemm_bt64(const u16* __restrict__ A,
                                                 const u16* __restrict__ Bt,
                                                 const float* __restrict__ bias,
                                                 float* __restrict__ C,
                                                 int N, int K) {
  __shared__ __align__(16) u16 smem[2][6144];   // [buf][As 2048 | Bs 4096]
  int t = threadIdx.x;
  int w = t >> 6, l = t & 63;
  int lr = l & 15, lg = l >> 4;

  int nwg = gridDim.x * gridDim.y;
  int bid = blockIdx.y * gridDim.x + blockIdx.x;
  int orig = (bid & 7) * (nwg >> 3) + (bid >> 3);   // XCD-chunked remap
  int bx = orig % gridDim.x, by = orig / gridDim.x;
  int m0 = by * 64, n0 = bx * 128;

  f32x4 acc[4][2];
#pragma unroll
  for (int i = 0; i < 4; ++i)
#pragma unroll
    for (int j = 0; j < 2; ++j)
      acc[i][j] = f32x4{0.f, 0.f, 0.f, 0.f};

  int ra = w * 16 + (l >> 2);
  int ca = (l & 3) ^ ((ra >> 1) & 3);
  int rb1 = ra + 64;
  int cb1 = (l & 3) ^ ((rb1 >> 1) & 3);
  const u16* gA  = A  + (size_t)(m0 + ra) * K + ca * 8;
  const u16* gB0 = Bt + (size_t)(n0 + ra) * K + ca * 8;
  const u16* gB1 = Bt + (size_t)(n0 + rb1) * K + cb1 * 8;
  int oA  = (w * 16) * 32;
  int oB0 = 2048 + (w * 16) * 32;
  int oB1 = 2048 + (64 + w * 16) * 32;

#define STAGE(K0, BUF) {                                   \
    gload_lds16(gA + (K0), &smem[BUF][oA]);                \
    gload_lds16(gB0 + (K0), &smem[BUF][oB0]);              \
    gload_lds16(gB1 + (K0), &smem[BUF][oB1]);              }

  STAGE(0, 0);
  __syncthreads();
  int cur = 0;
  for (int k0 = 0; k0 < K; k0 += 32) {
    if (k0 + 32 < K) STAGE(k0 + 32, cur ^ 1);
    const u16* As = smem[cur];
    const u16* Bs = smem[cur] + 2048;
    bf16x8 af[4], bfr[2];
#pragma unroll
    for (int mi = 0; mi < 4; ++mi) {
      int row = mi * 16 + lr;
      af[mi] = *(const bf16x8*)(As + row * 32 + ((lg ^ ((row >> 1) & 3)) << 3));
    }
#pragma unroll
    for (int ni = 0; ni < 2; ++ni) {
      int row = w * 32 + ni * 16 + lr;
      bfr[ni] = *(const bf16x8*)(Bs + row * 32 + ((lg ^ ((row >> 1) & 3)) << 3));
    }
    __builtin_amdgcn_s_setprio(1);
#pragma unroll
    for (int mi = 0; mi < 4; ++mi)
#pragma unroll
      for (int ni = 0; ni < 2; ++ni)
        acc[mi][ni] = MFMA16(af[mi], bfr[ni], acc[mi][ni]);
    __builtin_amdgcn_s_setprio(0);
    __syncthreads();
    cur ^= 1;
  }
#undef STAGE

#pragma unroll
  for (int mi = 0; mi < 4; ++mi)
#pragma unroll
    for (int ni = 0; ni < 2; ++ni)
#pragma unroll
      for (int rg = 0; rg < 4; ++rg) {
        int row = m0 + mi * 16 + lg * 4 + rg;
        int col = n0 + w * 32 + ni * 16 + lr;
        C[(size_t)row * N + col] = acc[mi][ni][rg] + bias[col];
      }
}

// ======== attention tile (swapped QK^T -> C[k][q], log2 domain, no-max) =====
__device__ __forceinline__ void attn_tile(const u16* Ks, const u16* Vs,
                                          bf16x8 q0, bf16x8 q1, f32x4* o,
                                          float& l_run, bool diag,
                                          int w, int l, int lr, int lg) {
  f32x4 s[4];
  __builtin_amdgcn_s_setprio(1);
#pragma unroll
  for (int ct = 0; ct < 4; ++ct) {
    int row = ct * 16 + lr;
    bf16x8 kf0 = *(const bf16x8*)(Ks + ((row * 64 + lg * 8) ^ ((row & 7) << 3)));
    bf16x8 kf1 = *(const bf16x8*)(Ks + ((row * 64 + 32 + lg * 8) ^ ((row & 7) << 3)));
    f32x4 z = f32x4{0.f, 0.f, 0.f, 0.f};
    z = MFMA16(kf0, q0, z);
    z = MFMA16(kf1, q1, z);
    s[ct] = z;
  }
  __builtin_amdgcn_s_setprio(0);
  if (diag) {
    int qrel = w * 16 + lr;
#pragma unroll
    for (int ct = 0; ct < 4; ++ct)
#pragma unroll
      for (int rg = 0; rg < 4; ++rg)
        if ((ct * 16 + lg * 4 + rg) > qrel) s[ct][rg] = -1e30f;
  }
  float ps = 0.f;
#pragma unroll
  for (int ct = 0; ct < 4; ++ct)
#pragma unroll
    for (int rg = 0; rg < 4; ++rg) {
      float p = fexp2(s[ct][rg]);
      s[ct][rg] = p;
      ps += p;
    }
  l_run += sum_lg(ps);

  unsigned W00 = cvtpk_bf16(s[0][0], s[0][1]);
  unsigned W01 = cvtpk_bf16(s[0][2], s[0][3]);
  unsigned W10 = cvtpk_bf16(s[1][0], s[1][1]);
  unsigned W11 = cvtpk_bf16(s[1][2], s[1][3]);
  unsigned W20 = cvtpk_bf16(s[2][0], s[2][1]);
  unsigned W21 = cvtpk_bf16(s[2][2], s[2][3]);
  unsigned W30 = cvtpk_bf16(s[3][0], s[3][1]);
  unsigned W31 = cvtpk_bf16(s[3][2], s[3][3]);
  SWAP32(W00, W10); SWAP16(W00, W10);
  SWAP32(W01, W11); SWAP16(W01, W11);
  SWAP32(W20, W30); SWAP16(W20, W30);
  SWAP32(W21, W31); SWAP16(W21, W31);
  union { unsigned u[4]; bf16x8 v; } P0, P1;
  P0.u[0] = W00; P0.u[1] = W01; P0.u[2] = W10; P0.u[3] = W11;
  P1.u[0] = W20; P1.u[1] = W21; P1.u[2] = W30; P1.u[3] = W31;

  __builtin_amdgcn_s_setprio(1);
#pragma unroll
  for (int dt = 0; dt < 4; ++dt) {
    int row = dt * 16 + lr;
    bf16x8 vf0 = *(const bf16x8*)(Vs + ((row * 64 + lg * 8) ^ ((row & 7) << 3)));
    bf16x8 vf1 = *(const bf16x8*)(Vs + ((row * 64 + 32 + lg * 8) ^ ((row & 7) << 3)));
    o[dt] = MFMA16(P0.v, vf0, o[dt]);
    o[dt] = MFMA16(P1.v, vf1, o[dt]);
  }
  __builtin_amdgcn_s_setprio(0);
}

// ---------------- flash attention, causal, paired q-tiles, KV-SPLIT ----------
__global__ __launch_bounds__(256, 4) void attn_kernel(const u16* __restrict__ qkv,
                                                      const u16* __restrict__ Vt,
                                                      u16* __restrict__ po0,
                                                      u16* __restrict__ po1,
                                                      float* __restrict__ pl) {
  __shared__ __align__(16) u16 Ks[2][64 * 64];
  __shared__ __align__(16) u16 Vs[2][64 * 64];
  int bid = blockIdx.y * 32 + blockIdx.x;
  int orig = (bid & 7) * 128 + (bid >> 3);   // XCD chunk: 4 bh per XCD
  int half = orig & 1;
  int qtA = (orig >> 1) & 15;
  int bh = orig >> 5;
  int qtB = 31 - qtA;
  int m = (qtA >= 8) ? 8 : (15 - qtA);       // split point: 16/17 units each
  int kts = half ? m : 0;
  int kte = half ? (qtB + 1) : m;
  int b = bh >> 4, h = bh & 15;
  int t = threadIdx.x, w = t >> 6, l = t & 63;
  int lr = l & 15, lg = l >> 4;

  const u16* qbase = qkv + (size_t)b * S_LEN * 3072 + h * 64;
  int qrA = qtA * 64 + w * 16 + lr;
  int qrB = qtB * 64 + w * 16 + lr;
  bf16x8 qA0 = *(const bf16x8*)(qbase + (size_t)qrA * 3072 + lg * 8);
  bf16x8 qA1 = *(const bf16x8*)(qbase + (size_t)qrA * 3072 + 32 + lg * 8);
  bf16x8 qB0 = *(const bf16x8*)(qbase + (size_t)qrB * 3072 + lg * 8);
  bf16x8 qB1 = *(const bf16x8*)(qbase + (size_t)qrB * 3072 + 32 + lg * 8);

  f32x4 oA[4], oB[4];
#pragma unroll
  for (int i = 0; i < 4; ++i) { oA[i] = f32x4{0.f,0.f,0.f,0.f}; oB[i] = f32x4{0.f,0.f,0.f,0.f}; }
  float lA = 0.f, lB = 0.f;

  int r0s = t >> 3, r1s = r0s + 32;
  int soff = (t & 7) * 8;
  int e0 = (r0s * 64 + soff) ^ ((r0s & 7) << 3);
  int e1 = (r1s * 64 + soff) ^ ((r1s & 7) << 3);
  const u16* Kg = qkv + (size_t)b * S_LEN * 3072 + 1024 + h * 64 + soff;
  const u16* Vg = Vt + (size_t)bh * 64 * S_LEN + soff;

  uint4 k0r, k1r, v0r, v1r;
#define ISSUE(KT) {                                                     \
    int kk0 = (KT) * 64;                                                \
    k0r = *(const uint4*)(Kg + (size_t)(kk0 + r0s) * 3072);             \
    k1r = *(const uint4*)(Kg + (size_t)(kk0 + r1s) * 3072);             \
    v0r = *(const uint4*)(Vg + (size_t)r0s * S_LEN + kk0);              \
    v1r = *(const uint4*)(Vg + (size_t)r1s * S_LEN + kk0);              }

  ISSUE(kts);
  *(uint4*)(Ks[0] + e0) = k0r;
  *(uint4*)(Ks[0] + e1) = k1r;
  *(uint4*)(Vs[0] + e0) = v0r;
  *(uint4*)(Vs[0] + e1) = v1r;
  if (kts + 1 < kte) ISSUE(kts + 1);
  __syncthreads();

  int cur = 0;
  for (int kt = kts; kt < kte; ++kt) {
    if (kt + 1 < kte) {
      u16* Kd = Ks[cur ^ 1];
      u16* Vd = Vs[cur ^ 1];
      *(uint4*)(Kd + e0) = k0r;
      *(uint4*)(Kd + e1) = k1r;
      *(uint4*)(Vd + e0) = v0r;
      *(uint4*)(Vd + e1) = v1r;
    }
    if (kt + 2 < kte) ISSUE(kt + 2);
    const u16* Kc = Ks[cur];
    const u16* Vc = Vs[cur];
    if (kt <= qtA)
      attn_tile(Kc, Vc, qA0, qA1, oA, lA, kt == qtA, w, l, lr, lg);
    attn_tile(Kc, Vc, qB0, qB1, oB, lB, kt == qtB, w, l, lr, lg);
    __syncthreads();
    cur ^= 1;
  }
#undef ISSUE

  u16* po = half ? po1 : po0;
  float* plh = pl + half * 65536;
#pragma unroll
  for (int dt = 0; dt < 4; ++dt)
#pragma unroll
    for (int rg = 0; rg < 4; ++rg) {
      int d = dt * 16 + lr;
      int qA_ = qtA * 64 + w * 16 + lg * 4 + rg;
      int qB_ = qtB * 64 + w * 16 + lg * 4 + rg;
      po[(size_t)(b * S_LEN + qA_) * 1024 + h * 64 + d] = f2bf(oA[dt][rg]);
      po[(size_t)(b * S_LEN + qB_) * 1024 + h * 64 + d] = f2bf(oB[dt][rg]);
    }
  if (lg == 0) {
    plh[bh * 2048 + qtA * 64 + w * 16 + lr] = lA;
    plh[bh * 2048 + qtB * 64 + w * 16 + lr] = lB;
  }
}

// ---------------- combine: out = (po0 + po1) * rcp(l0 + l1) -----------------
__global__ __launch_bounds__(256) void attn_combine(const u16* po0,
                                                    const u16* __restrict__ po1,
                                                    const float* __restrict__ pl,
                                                    u16* out) {
  int i = (blockIdx.x * 256 + threadIdx.x) * 8;
  int row = i >> 10;                 // b*2048 + q
  int h = (i & 1023) >> 6;
  int bh = (row >> 11) * 16 + h;
  int q = row & 2047;
  float r = frcp(pl[bh * 2048 + q] + pl[65536 + bh * 2048 + q]);
  bf16x8 a = *(const bf16x8*)(po0 + i);
  bf16x8 c = *(const bf16x8*)(po1 + i);
  union { u16 u[8]; bf16x8 v; } o;
#pragma unroll
  for (int j = 0; j < 8; ++j)
    o.u[j] = f2bf((bf2f((u16)a[j]) + bf2f((u16)c[j])) * r);
  *(bf16x8*)(out + i) = o.v;
}

// ---------------- launcher ----------------
extern "C" void kernel_launch(void* const* d_in, const int* in_sizes, int n_in,
                              void* d_out, int out_size, void* d_ws, size_t ws_size,
                              hipStream_t stream) {
  const float* x     = (const float*)d_in[0];
  const float* w_qkv = (const float*)d_in[1];
  const float* b_qkv = (const float*)d_in[2];
  const float* w_out = (const float*)d_in[3];
  const float* b_out = (const float*)d_in[4];
  float* out = (float*)d_out;

  // ws layout (56 MB) with liveness-based aliasing:
  //  0-8   : x_bf (dead after gemm1)  / po1
  //  8-14  : wqkvT (dead after gemm1) / pl (512 KB)
  //  14-16 : woutT (live until gemm2)
  //  16-40 : qkv (V third unused — V goes straight to Vt)
  //  40-48 : Vt
  //  48-56 : po0 / attnb (combine output aliases po0)
  char* ws = (char*)d_ws;
  u16* x_bf   = (u16*)(ws);
  u16* po1    = (u16*)(ws);
  u16* wqkvT  = (u16*)(ws + ( 8ull << 20));
  float* pl   = (float*)(ws + ( 8ull << 20));
  u16* woutT  = (u16*)(ws + (14ull << 20));
  u16* qkv    = (u16*)(ws + (16ull << 20));
  u16* Vt     = (u16*)(ws + (40ull << 20));
  u16* po0    = (u16*)(ws + (48ull << 20));
  u16* attnb  = (u16*)(ws + (48ull << 20));

  prep<<<4096 + 1024, 256, 0, stream>>>(x, w_qkv, w_out, x_bf, wqkvT, woutT);
  // Q columns (first 1024) pre-scaled into exp2/log2 domain for attention;
  // V columns transposed straight into Vt by the epilogue.
  gemm_qkv<<<dim3(12, 16), 512, 0, stream>>>(x_bf, wqkvT, b_qkv, qkv, Vt,
                                             LOG2E_DIV8);
  attn_kernel<<<dim3(32, 32), 256, 0, stream>>>(qkv, Vt, po0, po1, pl);
  attn_combine<<<MTOT * 1024 / (256 * 8), 256, 0, stream>>>(po0, po1, pl, attnb);
  gemm_bt64<<<dim3(8, 64), 256, 0, stream>>>(attnb, woutT, b_out, out, 1024, 1024);
}

// Round 14
// 101.669 us; speedup vs baseline: 1.0623x; 1.0623x over previous
//
#include <hip/hip_runtime.h>

typedef unsigned short u16;
typedef __attribute__((ext_vector_type(8))) short bf16x8;
typedef __attribute__((ext_vector_type(4))) float f32x4;

#define S_LEN 2048
#define MTOT  4096   // B*S
#define LOG2E_DIV8 0.1803368784f   // 0.125 * log2(e)

__device__ inline u16 f2bf(float f) {
  union { float f; unsigned u; } x; x.f = f;
  unsigned r = x.u + 0x7fffu + ((x.u >> 16) & 1u);
  return (u16)(r >> 16);
}
__device__ inline float bf2f(u16 u) {
  union { unsigned u; float f; } x; x.u = ((unsigned)u) << 16;
  return x.f;
}

__device__ __forceinline__ unsigned cvtpk_bf16(float lo, float hi) {
  unsigned r;
  asm("v_cvt_pk_bf16_f32 %0, %1, %2" : "=v"(r) : "v"(lo), "v"(hi));
  return r;
}
__device__ __forceinline__ float fexp2(float x) {
  float r;
  asm("v_exp_f32 %0, %1" : "=v"(r) : "v"(x));
  return r;
}
__device__ __forceinline__ float frcp(float x) {
  float r;
  asm("v_rcp_f32 %0, %1" : "=v"(r) : "v"(x));
  return r;
}

// --- gfx950 permlane swaps (both operands updated) ---
#define SWAP32(a, b) asm("v_permlane32_swap_b32 %0, %1" : "+v"(a), "+v"(b))
#define SWAP16(a, b) asm("v_permlane16_swap_b32 %0, %1" : "+v"(a), "+v"(b))

// sum of x over the 4 row-groups (lane bits 4-5), result in every lane
__device__ __forceinline__ float sum_lg(float x) {
  float a = x, b = x;
  SWAP32(a, b);
  float s = a + b;
  float c = s, d = s;
  SWAP16(c, d);
  return c + d;
}

typedef __attribute__((address_space(1))) const unsigned int gu32;
typedef __attribute__((address_space(3))) unsigned int lu32;
__device__ __forceinline__ void gload_lds16(const void* g, void* l) {
  __builtin_amdgcn_global_load_lds((gu32*)g, (lu32*)l, 16, 0, 0);
}

#define MFMA16(a, b, c) __builtin_amdgcn_mfma_f32_16x16x32_bf16((a), (b), (c), 0, 0, 0)
#define BAR  __builtin_amdgcn_s_barrier()
#define VMC5 asm volatile("s_waitcnt vmcnt(5)" ::: "memory")
#define VMC0 asm volatile("s_waitcnt vmcnt(0)" ::: "memory")

// ---- prep: x cast (blocks 0..4095) + weight transpose/cast (blocks 4096+) ----
__global__ __launch_bounds__(256) void prep(const float* __restrict__ x,
                                            const float* __restrict__ wqkv,
                                            const float* __restrict__ wout,
                                            u16* __restrict__ x_bf,
                                            u16* __restrict__ dqkv,
                                            u16* __restrict__ dwout) {
  __shared__ float tile[64][65];
  int bid = blockIdx.x;
  int t = threadIdx.x;
  if (bid < 4096) {
    int i = (bid * 256 + t) * 4;
    float4 v = *(const float4*)(x + i);
    ushort4 o;
    o.x = f2bf(v.x); o.y = f2bf(v.y); o.z = f2bf(v.z); o.w = f2bf(v.w);
    *(ushort4*)(x_bf + i) = o;
    return;
  }
  int idx = bid - 4096;
  int bx = idx & 63, by = idx >> 6;
  const float* src; u16* dst; int N, n0;
  if (bx < 48) { src = wqkv; dst = dqkv; N = 3072; n0 = bx * 64; }
  else         { src = wout; dst = dwout; N = 1024; n0 = (bx - 48) * 64; }
  int K = 1024, k0 = by * 64;
  for (int i = 0; i < 16; ++i) {
    int id2 = t + 256 * i;
    int r = id2 >> 6, c = id2 & 63;
    tile[r][c] = src[(size_t)(k0 + r) * N + n0 + c];
  }
  __syncthreads();
  for (int i = 0; i < 16; ++i) {
    int id2 = t + 256 * i;
    int r = id2 >> 6, c = id2 & 63;
    dst[(size_t)(n0 + r) * K + k0 + c] = f2bf(tile[c][r]);
  }
}

// ---- GEMM1 (QKV): 256x192 tile, BK=64, 8 waves, 8-phase counted-vmcnt ------
// Grid 16x16 = 256 blocks = EXACTLY 1/CU (fixes the 192-block 75%-utilization
// loss of the 256x256 tiling).  LDS 112KB: A 2buf x 2half x [128][64];
// B 2buf x 3third x [64][64] (thirds contiguous -> B buf = [192][64]).
// Chunk-swizzle c^=(r&7), pre-swizzled global source.  vmcnt(5) checkpoints.
__global__ __launch_bounds__(512, 1) void gemm_qkv(const u16* __restrict__ A,
                                                   const u16* __restrict__ Bt,
                                                   const float* __restrict__ bias,
                                                   u16* __restrict__ qkv,
                                                   u16* __restrict__ Vt,
                                                   float qscale) {
  __shared__ __align__(16) u16 smem[57344];   // A: [0,32768) ; B: [32768,57344)
  int t = threadIdx.x;
  int w = t >> 6, l = t & 63;
  int wr = w >> 2, wcn = w & 3;       // wave grid 2(M) x 4(N), per-wave 128x48
  int lr = l & 15, lg = l >> 4;

  int bid = blockIdx.y * 16 + blockIdx.x;
  int orig = (bid & 7) * 32 + (bid >> 3);    // XCD-chunked remap (256 % 8 == 0)
  int bx = orig & 15, by = orig >> 4;
  int m0 = by * 256, n0 = bx * 192;

  f32x4 acc[8][3];
#pragma unroll
  for (int i = 0; i < 8; ++i)
#pragma unroll
    for (int j = 0; j < 3; ++j)
      acc[i][j] = f32x4{0.f, 0.f, 0.f, 0.f};

  // staging: thread t covers (row block + (t>>3), chunk t&7), global chunk
  // pre-swizzled by row&7 so LDS[r][c] = G[r][c ^ (r&7)]
  int cg = ((t & 7) ^ ((t >> 3) & 7)) * 8;
  const u16* gAh[2][2];
  const u16* gB3[3];
#pragma unroll
  for (int h = 0; h < 2; ++h)
#pragma unroll
    for (int j = 0; j < 2; ++j)
      gAh[h][j] = A + (size_t)(m0 + h * 128 + j * 64 + (t >> 3)) * 1024 + cg;
#pragma unroll
  for (int th = 0; th < 3; ++th)
    gB3[th] = Bt + (size_t)(n0 + th * 64 + (t >> 3)) * 1024 + cg;

#define STG_A(kt, h) {                                                  \
    u16* d_ = smem + (((kt) & 1) * 2 + (h)) * 8192 + t * 8;             \
    gload_lds16(gAh[h][0] + (size_t)(kt) * 64, d_);                     \
    gload_lds16(gAh[h][1] + (size_t)(kt) * 64, d_ + 4096);              }
#define STG_B3(kt, th) {                                                \
    u16* d_ = smem + 32768 + (((kt) & 1) * 3 + (th)) * 4096 + t * 8;    \
    gload_lds16(gB3[th] + (size_t)(kt) * 64, d_);                       }

  // fragment chunk offsets (swizzle-corrected; row&7 == lr&7 for all frags)
  int co0 = (lg ^ (lr & 7)) << 3;
  int co1 = ((4 + lg) ^ (lr & 7)) << 3;
  const u16* bA[2] = { smem + wr * 8192, smem + (2 + wr) * 8192 };
  const u16* bB[2] = { smem + 32768, smem + 32768 + 12288 };
  int rB = (48 * wcn + lr) * 64;

  bf16x8 AF[4][2], Bf[3][2];
#define LDA(B_, OFF) { const u16* p_ = bA[B_] + (OFF) + lr * 64;        \
    _Pragma("unroll") for (int mi = 0; mi < 4; ++mi) {                  \
      AF[mi][0] = *(const bf16x8*)(p_ + mi * 1024 + co0);               \
      AF[mi][1] = *(const bf16x8*)(p_ + mi * 1024 + co1); } }
#define LDB(B_) { const u16* p_ = bB[B_] + rB;                          \
    _Pragma("unroll") for (int ni = 0; ni < 3; ++ni) {                  \
      Bf[ni][0] = *(const bf16x8*)(p_ + ni * 1024 + co0);               \
      Bf[ni][1] = *(const bf16x8*)(p_ + ni * 1024 + co1); } }
#define QUADa(MO) {                                                     \
    __builtin_amdgcn_s_setprio(1);                                      \
    _Pragma("unroll") for (int mi = 0; mi < 4; ++mi)                    \
    _Pragma("unroll") for (int ni = 0; ni < 2; ++ni) {                  \
      acc[MO + mi][ni] = MFMA16(AF[mi][0], Bf[ni][0], acc[MO + mi][ni]); \
      acc[MO + mi][ni] = MFMA16(AF[mi][1], Bf[ni][1], acc[MO + mi][ni]); } \
    __builtin_amdgcn_s_setprio(0); }
#define QUADb(MO) {                                                     \
    __builtin_amdgcn_s_setprio(1);                                      \
    _Pragma("unroll") for (int mi = 0; mi < 4; ++mi) {                  \
      acc[MO + mi][2] = MFMA16(AF[mi][0], Bf[2][0], acc[MO + mi][2]);   \
      acc[MO + mi][2] = MFMA16(AF[mi][1], Bf[2][1], acc[MO + mi][2]); } \
    __builtin_amdgcn_s_setprio(0); }

  // prologue: K-tile 0 fully (7 gloads) + K-tile 1 {Bt0,Bt1,Bt2,Ah0} (5)
  STG_B3(0, 0); STG_B3(0, 1); STG_B3(0, 2); STG_A(0, 0); STG_A(0, 1);
  STG_B3(1, 0); STG_B3(1, 1); STG_B3(1, 2); STG_A(1, 0);
  VMC5;                        // K-tile 0 complete; K1's 5 stay in flight
  BAR;

  for (int i = 0; i < 8; ++i) {
    bool s = (i < 7);
    int k0t = 2 * i, k1t = 2 * i + 1;
    // ph0: read tile k0t (A m0-3 + all B); stage Ah1(k1t)
    LDA(0, 0); LDB(0);
    STG_A(k1t, 1);
    BAR; QUADa(0); BAR;
    // ph1: stage Bt0,Bt1(k0t+2)
    if (s) { STG_B3(k0t + 2, 0); STG_B3(k0t + 2, 1); }
    BAR; QUADb(0); BAR;
    // ph2: read A(m4-7); stage Bt2(k0t+2)
    LDA(0, 4096);
    if (s) STG_B3(k0t + 2, 2);
    BAR; QUADa(4); BAR;
    // ph3: stage Ah0(k0t+2); CHECKPOINT
    if (s) STG_A(k0t + 2, 0);
    if (i == 7) { VMC0; } else { VMC5; }
    BAR; QUADb(4); BAR;
    // ph4: read tile k1t (A m0-3 + all B); stage Ah1(k0t+2)
    LDA(1, 0); LDB(1);
    if (s) STG_A(k0t + 2, 1);
    BAR; QUADa(0); BAR;
    // ph5: stage Bt0,Bt1(k1t+2)
    if (s) { STG_B3(k1t + 2, 0); STG_B3(k1t + 2, 1); }
    BAR; QUADb(0); BAR;
    // ph6: read A(m4-7); stage Bt2(k1t+2)
    LDA(1, 4096);
    if (s) STG_B3(k1t + 2, 2);
    BAR; QUADa(4); BAR;
    // ph7: stage Ah0(k1t+2); CHECKPOINT
    if (s) STG_A(k1t + 2, 0);
    VMC5;
    BAR; QUADb(4); BAR;
  }
#undef STG_A
#undef STG_B3
#undef LDA
#undef LDB
#undef QUADa
#undef QUADb

  // ---- epilogue ----
  // Q/K columns (col < 2048): per-element bf16 write; Q cols scaled.
#pragma unroll
  for (int ni = 0; ni < 3; ++ni) {
    int cb = n0 + wcn * 48 + ni * 16;      // 16-aligned; class uniform per ni
    if (cb < 2048) {
      float qs = (cb < 1024) ? qscale : 1.0f;
#pragma unroll
      for (int mi = 0; mi < 8; ++mi)
#pragma unroll
        for (int rg = 0; rg < 4; ++rg) {
          int row = m0 + wr * 128 + mi * 16 + lg * 4 + rg;
          int col = cb + lr;
          qkv[(size_t)row * 3072 + col] = f2bf((acc[mi][ni][rg] + bias[col]) * qs);
        }
    }
  }
  // V columns (64-col groups g with n0+64g >= 2048): LDS transpose -> Vt.
  int gvs = 32 - 3 * bx;                   // first V group (may exceed 2)
  if (gvs < 0) gvs = 0;
  int b = by >> 3, sbase = (by & 7) * 256;
  u16* Vl = smem;
#pragma unroll
  for (int g = 0; g < 3; ++g) {
    if (g < gvs) continue;                 // uniform per block
    __syncthreads();
#pragma unroll
    for (int ni = 0; ni < 3; ++ni) {
      int blk = 3 * wcn + ni;              // 16-col block index in tile
      if (blk >= 4 * g && blk < 4 * g + 4) {
        int d = (blk - 4 * g) * 16 + lr;
        int col = n0 + blk * 16 + lr;
#pragma unroll
        for (int mi = 0; mi < 8; ++mi) {
          int srow = wr * 128 + mi * 16 + lg * 4;
          union { u16 u[4]; unsigned long long q; } pk;
#pragma unroll
          for (int rg = 0; rg < 4; ++rg)
            pk.u[rg] = f2bf(acc[mi][ni][rg] + bias[col]);
          *(unsigned long long*)&Vl[d * 272 + srow] = pk.q;
        }
      }
    }
    __syncthreads();
    int hv = 3 * bx + g - 32;
    int d = t >> 3, sc = (t & 7) * 32;
    u16* dst = Vt + ((size_t)((b * 16 + hv) * 64 + d)) * 2048 + sbase + sc;
    const u16* src = Vl + d * 272 + sc;
#pragma unroll
    for (int j = 0; j < 4; ++j)
      *(uint4*)(dst + j * 8) = *(const uint4*)(src + j * 8);
  }
}

// ------------- GEMM2: 64x128 tile, 4 waves of 64x32, 2-phase dbuf -----------
__global__ __launch_bounds__(256) void gemm_bt64(const u16* __restrict__ A,
                                                 const u16* __restrict__ Bt,
                                                 const float* __restrict__ bias,
                                                 float* __restrict__ C,
                                                 int N, int K) {
  __shared__ __align__(16) u16 smem[2][6144];   // [buf][As 2048 | Bs 4096]
  int t = threadIdx.x;
  int w = t >> 6, l = t & 63;
  int lr = l & 15, lg = l >> 4;

  int nwg = gridDim.x * gridDim.y;
  int bid = blockIdx.y * gridDim.x + blockIdx.x;
  int orig = (bid & 7) * (nwg >> 3) + (bid >> 3);   // XCD-chunked remap
  int bx = orig % gridDim.x, by = orig / gridDim.x;
  int m0 = by * 64, n0 = bx * 128;

  f32x4 acc[4][2];
#pragma unroll
  for (int i = 0; i < 4; ++i)
#pragma unroll
    for (int j = 0; j < 2; ++j)
      acc[i][j] = f32x4{0.f, 0.f, 0.f, 0.f};

  int ra = w * 16 + (l >> 2);
  int ca = (l & 3) ^ ((ra >> 1) & 3);
  int rb1 = ra + 64;
  int cb1 = (l & 3) ^ ((rb1 >> 1) & 3);
  const u16* gA  = A  + (size_t)(m0 + ra) * K + ca * 8;
  const u16* gB0 = Bt + (size_t)(n0 + ra) * K + ca * 8;
  const u16* gB1 = Bt + (size_t)(n0 + rb1) * K + cb1 * 8;
  int oA  = (w * 16) * 32;
  int oB0 = 2048 + (w * 16) * 32;
  int oB1 = 2048 + (64 + w * 16) * 32;

#define STAGE(K0, BUF) {                                   \
    gload_lds16(gA + (K0), &smem[BUF][oA]);                \
    gload_lds16(gB0 + (K0), &smem[BUF][oB0]);              \
    gload_lds16(gB1 + (K0), &smem[BUF][oB1]);              }

  STAGE(0, 0);
  __syncthreads();
  int cur = 0;
  for (int k0 = 0; k0 < K; k0 += 32) {
    if (k0 + 32 < K) STAGE(k0 + 32, cur ^ 1);
    const u16* As = smem[cur];
    const u16* Bs = smem[cur] + 2048;
    bf16x8 af[4], bfr[2];
#pragma unroll
    for (int mi = 0; mi < 4; ++mi) {
      int row = mi * 16 + lr;
      af[mi] = *(const bf16x8*)(As + row * 32 + ((lg ^ ((row >> 1) & 3)) << 3));
    }
#pragma unroll
    for (int ni = 0; ni < 2; ++ni) {
      int row = w * 32 + ni * 16 + lr;
      bfr[ni] = *(const bf16x8*)(Bs + row * 32 + ((lg ^ ((row >> 1) & 3)) << 3));
    }
    __builtin_amdgcn_s_setprio(1);
#pragma unroll
    for (int mi = 0; mi < 4; ++mi)
#pragma unroll
      for (int ni = 0; ni < 2; ++ni)
        acc[mi][ni] = MFMA16(af[mi], bfr[ni], acc[mi][ni]);
    __builtin_amdgcn_s_setprio(0);
    __syncthreads();
    cur ^= 1;
  }
#undef STAGE

#pragma unroll
  for (int mi = 0; mi < 4; ++mi)
#pragma unroll
    for (int ni = 0; ni < 2; ++ni)
#pragma unroll
      for (int rg = 0; rg < 4; ++rg) {
        int row = m0 + mi * 16 + lg * 4 + rg;
        int col = n0 + w * 32 + ni * 16 + lr;
        C[(size_t)row * N + col] = acc[mi][ni][rg] + bias[col];
      }
}

// ======== attention tile (swapped QK^T -> C[k][q], log2 domain, no-max) =====
__device__ __forceinline__ void attn_tile(const u16* Ks, const u16* Vs,
                                          bf16x8 q0, bf16x8 q1, f32x4* o,
                                          float& l_run, bool diag,
                                          int w, int l, int lr, int lg) {
  f32x4 s[4];
  __builtin_amdgcn_s_setprio(1);
#pragma unroll
  for (int ct = 0; ct < 4; ++ct) {
    int row = ct * 16 + lr;
    bf16x8 kf0 = *(const bf16x8*)(Ks + ((row * 64 + lg * 8) ^ ((row & 7) << 3)));
    bf16x8 kf1 = *(const bf16x8*)(Ks + ((row * 64 + 32 + lg * 8) ^ ((row & 7) << 3)));
    f32x4 z = f32x4{0.f, 0.f, 0.f, 0.f};
    z = MFMA16(kf0, q0, z);
    z = MFMA16(kf1, q1, z);
    s[ct] = z;
  }
  __builtin_amdgcn_s_setprio(0);
  if (diag) {
    int qrel = w * 16 + lr;
#pragma unroll
    for (int ct = 0; ct < 4; ++ct)
#pragma unroll
      for (int rg = 0; rg < 4; ++rg)
        if ((ct * 16 + lg * 4 + rg) > qrel) s[ct][rg] = -1e30f;
  }
  float ps = 0.f;
#pragma unroll
  for (int ct = 0; ct < 4; ++ct)
#pragma unroll
    for (int rg = 0; rg < 4; ++rg) {
      float p = fexp2(s[ct][rg]);
      s[ct][rg] = p;
      ps += p;
    }
  l_run += sum_lg(ps);

  unsigned W00 = cvtpk_bf16(s[0][0], s[0][1]);
  unsigned W01 = cvtpk_bf16(s[0][2], s[0][3]);
  unsigned W10 = cvtpk_bf16(s[1][0], s[1][1]);
  unsigned W11 = cvtpk_bf16(s[1][2], s[1][3]);
  unsigned W20 = cvtpk_bf16(s[2][0], s[2][1]);
  unsigned W21 = cvtpk_bf16(s[2][2], s[2][3]);
  unsigned W30 = cvtpk_bf16(s[3][0], s[3][1]);
  unsigned W31 = cvtpk_bf16(s[3][2], s[3][3]);
  SWAP32(W00, W10); SWAP16(W00, W10);
  SWAP32(W01, W11); SWAP16(W01, W11);
  SWAP32(W20, W30); SWAP16(W20, W30);
  SWAP32(W21, W31); SWAP16(W21, W31);
  union { unsigned u[4]; bf16x8 v; } P0, P1;
  P0.u[0] = W00; P0.u[1] = W01; P0.u[2] = W10; P0.u[3] = W11;
  P1.u[0] = W20; P1.u[1] = W21; P1.u[2] = W30; P1.u[3] = W31;

  __builtin_amdgcn_s_setprio(1);
#pragma unroll
  for (int dt = 0; dt < 4; ++dt) {
    int row = dt * 16 + lr;
    bf16x8 vf0 = *(const bf16x8*)(Vs + ((row * 64 + lg * 8) ^ ((row & 7) << 3)));
    bf16x8 vf1 = *(const bf16x8*)(Vs + ((row * 64 + 32 + lg * 8) ^ ((row & 7) << 3)));
    o[dt] = MFMA16(P0.v, vf0, o[dt]);
    o[dt] = MFMA16(P1.v, vf1, o[dt]);
  }
  __builtin_amdgcn_s_setprio(0);
}

// ---------------- flash attention, causal, paired q-tiles, KV-SPLIT ----------
__global__ __launch_bounds__(256, 4) void attn_kernel(const u16* __restrict__ qkv,
                                                      const u16* __restrict__ Vt,
                                                      u16* __restrict__ po0,
                                                      u16* __restrict__ po1,
                                                      float* __restrict__ pl) {
  __shared__ __align__(16) u16 Ks[2][64 * 64];
  __shared__ __align__(16) u16 Vs[2][64 * 64];
  int bid = blockIdx.y * 32 + blockIdx.x;
  int orig = (bid & 7) * 128 + (bid >> 3);   // XCD chunk: 4 bh per XCD
  int half = orig & 1;
  int qtA = (orig >> 1) & 15;
  int bh = orig >> 5;
  int qtB = 31 - qtA;
  int m = (qtA >= 8) ? 8 : (15 - qtA);       // split point: 16/17 units each
  int kts = half ? m : 0;
  int kte = half ? (qtB + 1) : m;
  int b = bh >> 4, h = bh & 15;
  int t = threadIdx.x, w = t >> 6, l = t & 63;
  int lr = l & 15, lg = l >> 4;

  const u16* qbase = qkv + (size_t)b * S_LEN * 3072 + h * 64;
  int qrA = qtA * 64 + w * 16 + lr;
  int qrB = qtB * 64 + w * 16 + lr;
  bf16x8 qA0 = *(const bf16x8*)(qbase + (size_t)qrA * 3072 + lg * 8);
  bf16x8 qA1 = *(const bf16x8*)(qbase + (size_t)qrA * 3072 + 32 + lg * 8);
  bf16x8 qB0 = *(const bf16x8*)(qbase + (size_t)qrB * 3072 + lg * 8);
  bf16x8 qB1 = *(const bf16x8*)(qbase + (size_t)qrB * 3072 + 32 + lg * 8);

  f32x4 oA[4], oB[4];
#pragma unroll
  for (int i = 0; i < 4; ++i) { oA[i] = f32x4{0.f,0.f,0.f,0.f}; oB[i] = f32x4{0.f,0.f,0.f,0.f}; }
  float lA = 0.f, lB = 0.f;

  int r0s = t >> 3, r1s = r0s + 32;
  int soff = (t & 7) * 8;
  int e0 = (r0s * 64 + soff) ^ ((r0s & 7) << 3);
  int e1 = (r1s * 64 + soff) ^ ((r1s & 7) << 3);
  const u16* Kg = qkv + (size_t)b * S_LEN * 3072 + 1024 + h * 64 + soff;
  const u16* Vg = Vt + (size_t)bh * 64 * S_LEN + soff;

  uint4 k0r, k1r, v0r, v1r;
#define ISSUE(KT) {                                                     \
    int kk0 = (KT) * 64;                                                \
    k0r = *(const uint4*)(Kg + (size_t)(kk0 + r0s) * 3072);             \
    k1r = *(const uint4*)(Kg + (size_t)(kk0 + r1s) * 3072);             \
    v0r = *(const uint4*)(Vg + (size_t)r0s * S_LEN + kk0);              \
    v1r = *(const uint4*)(Vg + (size_t)r1s * S_LEN + kk0);              }

  ISSUE(kts);
  *(uint4*)(Ks[0] + e0) = k0r;
  *(uint4*)(Ks[0] + e1) = k1r;
  *(uint4*)(Vs[0] + e0) = v0r;
  *(uint4*)(Vs[0] + e1) = v1r;
  if (kts + 1 < kte) ISSUE(kts + 1);
  __syncthreads();

  int cur = 0;
  for (int kt = kts; kt < kte; ++kt) {
    if (kt + 1 < kte) {
      u16* Kd = Ks[cur ^ 1];
      u16* Vd = Vs[cur ^ 1];
      *(uint4*)(Kd + e0) = k0r;
      *(uint4*)(Kd + e1) = k1r;
      *(uint4*)(Vd + e0) = v0r;
      *(uint4*)(Vd + e1) = v1r;
    }
    if (kt + 2 < kte) ISSUE(kt + 2);
    const u16* Kc = Ks[cur];
    const u16* Vc = Vs[cur];
    if (kt <= qtA)
      attn_tile(Kc, Vc, qA0, qA1, oA, lA, kt == qtA, w, l, lr, lg);
    attn_tile(Kc, Vc, qB0, qB1, oB, lB, kt == qtB, w, l, lr, lg);
    __syncthreads();
    cur ^= 1;
  }
#undef ISSUE

  u16* po = half ? po1 : po0;
  float* plh = pl + half * 65536;
#pragma unroll
  for (int dt = 0; dt < 4; ++dt)
#pragma unroll
    for (int rg = 0; rg < 4; ++rg) {
      int d = dt * 16 + lr;
      int qA_ = qtA * 64 + w * 16 + lg * 4 + rg;
      int qB_ = qtB * 64 + w * 16 + lg * 4 + rg;
      po[(size_t)(b * S_LEN + qA_) * 1024 + h * 64 + d] = f2bf(oA[dt][rg]);
      po[(size_t)(b * S_LEN + qB_) * 1024 + h * 64 + d] = f2bf(oB[dt][rg]);
    }
  if (lg == 0) {
    plh[bh * 2048 + qtA * 64 + w * 16 + lr] = lA;
    plh[bh * 2048 + qtB * 64 + w * 16 + lr] = lB;
  }
}

// ---------------- combine: out = (po0 + po1) * rcp(l0 + l1) -----------------
__global__ __launch_bounds__(256) void attn_combine(const u16* po0,
                                                    const u16* __restrict__ po1,
                                                    const float* __restrict__ pl,
                                                    u16* out) {
  int i = (blockIdx.x * 256 + threadIdx.x) * 8;
  int row = i >> 10;                 // b*2048 + q
  int h = (i & 1023) >> 6;
  int bh = (row >> 11) * 16 + h;
  int q = row & 2047;
  float r = frcp(pl[bh * 2048 + q] + pl[65536 + bh * 2048 + q]);
  bf16x8 a = *(const bf16x8*)(po0 + i);
  bf16x8 c = *(const bf16x8*)(po1 + i);
  union { u16 u[8]; bf16x8 v; } o;
#pragma unroll
  for (int j = 0; j < 8; ++j)
    o.u[j] = f2bf((bf2f((u16)a[j]) + bf2f((u16)c[j])) * r);
  *(bf16x8*)(out + i) = o.v;
}

// ---------------- launcher ----------------
extern "C" void kernel_launch(void* const* d_in, const int* in_sizes, int n_in,
                              void* d_out, int out_size, void* d_ws, size_t ws_size,
                              hipStream_t stream) {
  const float* x     = (const float*)d_in[0];
  const float* w_qkv = (const float*)d_in[1];
  const float* b_qkv = (const float*)d_in[2];
  const float* w_out = (const float*)d_in[3];
  const float* b_out = (const float*)d_in[4];
  float* out = (float*)d_out;

  // ws layout (56 MB) with liveness-based aliasing:
  //  0-8   : x_bf (dead after gemm1)  / po1
  //  8-14  : wqkvT (dead after gemm1) / pl (512 KB)
  //  14-16 : woutT (live until gemm2)
  //  16-40 : qkv (V third unused — V goes straight to Vt)
  //  40-48 : Vt
  //  48-56 : po0 / attnb (combine output aliases po0)
  char* ws = (char*)d_ws;
  u16* x_bf   = (u16*)(ws);
  u16* po1    = (u16*)(ws);
  u16* wqkvT  = (u16*)(ws + ( 8ull << 20));
  float* pl   = (float*)(ws + ( 8ull << 20));
  u16* woutT  = (u16*)(ws + (14ull << 20));
  u16* qkv    = (u16*)(ws + (16ull << 20));
  u16* Vt     = (u16*)(ws + (40ull << 20));
  u16* po0    = (u16*)(ws + (48ull << 20));
  u16* attnb  = (u16*)(ws + (48ull << 20));

  prep<<<4096 + 1024, 256, 0, stream>>>(x, w_qkv, w_out, x_bf, wqkvT, woutT);
  // Q columns (first 1024) pre-scaled into exp2/log2 domain for attention;
  // V columns transposed straight into Vt by the epilogue.
  gemm_qkv<<<dim3(16, 16), 512, 0, stream>>>(x_bf, wqkvT, b_qkv, qkv, Vt,
                                             LOG2E_DIV8);
  attn_kernel<<<dim3(32, 32), 256, 0, stream>>>(qkv, Vt, po0, po1, pl);
  attn_combine<<<MTOT * 1024 / (256 * 8), 256, 0, stream>>>(po0, po1, pl, attnb);
  gemm_bt64<<<dim3(8, 64), 256, 0, stream>>>(attnb, woutT, b_out, out, 1024, 1024);
}

// Round 17
// 101.207 us; speedup vs baseline: 1.0672x; 1.0046x over previous
//
#include <hip/hip_runtime.h>

typedef unsigned short u16;
typedef __attribute__((ext_vector_type(8))) short bf16x8;
typedef __attribute__((ext_vector_type(4))) float f32x4;

#define S_LEN 2048
#define MTOT  4096   // B*S
#define LOG2E_DIV8 0.1803368784f   // 0.125 * log2(e)

__device__ inline u16 f2bf(float f) {
  union { float f; unsigned u; } x; x.f = f;
  unsigned r = x.u + 0x7fffu + ((x.u >> 16) & 1u);
  return (u16)(r >> 16);
}
__device__ inline float bf2f(u16 u) {
  union { unsigned u; float f; } x; x.u = ((unsigned)u) << 16;
  return x.f;
}

__device__ __forceinline__ unsigned cvtpk_bf16(float lo, float hi) {
  unsigned r;
  asm("v_cvt_pk_bf16_f32 %0, %1, %2" : "=v"(r) : "v"(lo), "v"(hi));
  return r;
}
__device__ __forceinline__ float fexp2(float x) {
  float r;
  asm("v_exp_f32 %0, %1" : "=v"(r) : "v"(x));
  return r;
}
__device__ __forceinline__ float frcp(float x) {
  float r;
  asm("v_rcp_f32 %0, %1" : "=v"(r) : "v"(x));
  return r;
}

// --- gfx950 permlane swaps (both operands updated) ---
#define SWAP32(a, b) asm("v_permlane32_swap_b32 %0, %1" : "+v"(a), "+v"(b))
#define SWAP16(a, b) asm("v_permlane16_swap_b32 %0, %1" : "+v"(a), "+v"(b))

// sum of x over the 4 row-groups (lane bits 4-5), result in every lane
__device__ __forceinline__ float sum_lg(float x) {
  float a = x, b = x;
  SWAP32(a, b);
  float s = a + b;
  float c = s, d = s;
  SWAP16(c, d);
  return c + d;
}

typedef __attribute__((address_space(1))) const unsigned int gu32;
typedef __attribute__((address_space(3))) unsigned int lu32;
__device__ __forceinline__ void gload_lds16(const void* g, void* l) {
  __builtin_amdgcn_global_load_lds((gu32*)g, (lu32*)l, 16, 0, 0);
}

#define MFMA16(a, b, c) __builtin_amdgcn_mfma_f32_16x16x32_bf16((a), (b), (c), 0, 0, 0)
#define BAR  __builtin_amdgcn_s_barrier()
#define VMC5 asm volatile("s_waitcnt vmcnt(5)" ::: "memory")
#define VMC0 asm volatile("s_waitcnt vmcnt(0)" ::: "memory")

// ---- prep: x cast (blocks 0..2047, 8 f32/thread) + weight transpose --------
__global__ __launch_bounds__(256) void prep(const float* __restrict__ x,
                                            const float* __restrict__ wqkv,
                                            const float* __restrict__ wout,
                                            u16* __restrict__ x_bf,
                                            u16* __restrict__ dqkv,
                                            u16* __restrict__ dwout) {
  __shared__ float tile[64][65];
  int bid = blockIdx.x;
  int t = threadIdx.x;
  if (bid < 2048) {
    int i = (bid * 256 + t) * 8;
    float4 v0 = *(const float4*)(x + i);
    float4 v1 = *(const float4*)(x + i + 4);
    union { u16 u[8]; uint4 q; } o;
    o.u[0] = f2bf(v0.x); o.u[1] = f2bf(v0.y); o.u[2] = f2bf(v0.z); o.u[3] = f2bf(v0.w);
    o.u[4] = f2bf(v1.x); o.u[5] = f2bf(v1.y); o.u[6] = f2bf(v1.z); o.u[7] = f2bf(v1.w);
    *(uint4*)(x_bf + i) = o.q;
    return;
  }
  int idx = bid - 2048;
  int bx = idx & 63, by = idx >> 6;
  const float* src; u16* dst; int N, n0;
  if (bx < 48) { src = wqkv; dst = dqkv; N = 3072; n0 = bx * 64; }
  else         { src = wout; dst = dwout; N = 1024; n0 = (bx - 48) * 64; }
  int K = 1024, k0 = by * 64;
  for (int i = 0; i < 16; ++i) {
    int id2 = t + 256 * i;
    int r = id2 >> 6, c = id2 & 63;
    tile[r][c] = src[(size_t)(k0 + r) * N + n0 + c];
  }
  __syncthreads();
  for (int i = 0; i < 16; ++i) {
    int id2 = t + 256 * i;
    int r = id2 >> 6, c = id2 & 63;
    dst[(size_t)(n0 + r) * K + k0 + c] = f2bf(tile[c][r]);
  }
}

// ---- GEMM1 (QKV): 256x192 tile, BK=64, 8 waves, 8-phase counted-vmcnt ------
__global__ __launch_bounds__(512, 1) void gemm_qkv(const u16* __restrict__ A,
                                                   const u16* __restrict__ Bt,
                                                   const float* __restrict__ bias,
                                                   u16* __restrict__ qkv,
                                                   u16* __restrict__ Vt,
                                                   float qscale) {
  __shared__ __align__(16) u16 smem[57344];   // A: [0,32768) ; B: [32768,57344)
  int t = threadIdx.x;
  int w = t >> 6, l = t & 63;
  int wr = w >> 2, wcn = w & 3;       // wave grid 2(M) x 4(N), per-wave 128x48
  int lr = l & 15, lg = l >> 4;

  int bid = blockIdx.y * 16 + blockIdx.x;
  int orig = (bid & 7) * 32 + (bid >> 3);    // XCD-chunked remap (256 % 8 == 0)
  int bx = orig & 15, by = orig >> 4;
  int m0 = by * 256, n0 = bx * 192;

  f32x4 acc[8][3];
#pragma unroll
  for (int i = 0; i < 8; ++i)
#pragma unroll
    for (int j = 0; j < 3; ++j)
      acc[i][j] = f32x4{0.f, 0.f, 0.f, 0.f};

  int cg = ((t & 7) ^ ((t >> 3) & 7)) * 8;
  const u16* gAh[2][2];
  const u16* gB3[3];
#pragma unroll
  for (int h = 0; h < 2; ++h)
#pragma unroll
    for (int j = 0; j < 2; ++j)
      gAh[h][j] = A + (size_t)(m0 + h * 128 + j * 64 + (t >> 3)) * 1024 + cg;
#pragma unroll
  for (int th = 0; th < 3; ++th)
    gB3[th] = Bt + (size_t)(n0 + th * 64 + (t >> 3)) * 1024 + cg;

#define STG_A(kt, h) {                                                  \
    u16* d_ = smem + (((kt) & 1) * 2 + (h)) * 8192 + t * 8;             \
    gload_lds16(gAh[h][0] + (size_t)(kt) * 64, d_);                     \
    gload_lds16(gAh[h][1] + (size_t)(kt) * 64, d_ + 4096);              }
#define STG_B3(kt, th) {                                                \
    u16* d_ = smem + 32768 + (((kt) & 1) * 3 + (th)) * 4096 + t * 8;    \
    gload_lds16(gB3[th] + (size_t)(kt) * 64, d_);                       }

  int co0 = (lg ^ (lr & 7)) << 3;
  int co1 = ((4 + lg) ^ (lr & 7)) << 3;
  const u16* bA[2] = { smem + wr * 8192, smem + (2 + wr) * 8192 };
  const u16* bB[2] = { smem + 32768, smem + 32768 + 12288 };
  int rB = (48 * wcn + lr) * 64;

  bf16x8 AF[4][2], Bf[3][2];
#define LDA(B_, OFF) { const u16* p_ = bA[B_] + (OFF) + lr * 64;        \
    _Pragma("unroll") for (int mi = 0; mi < 4; ++mi) {                  \
      AF[mi][0] = *(const bf16x8*)(p_ + mi * 1024 + co0);               \
      AF[mi][1] = *(const bf16x8*)(p_ + mi * 1024 + co1); } }
#define LDB(B_) { const u16* p_ = bB[B_] + rB;                          \
    _Pragma("unroll") for (int ni = 0; ni < 3; ++ni) {                  \
      Bf[ni][0] = *(const bf16x8*)(p_ + ni * 1024 + co0);               \
      Bf[ni][1] = *(const bf16x8*)(p_ + ni * 1024 + co1); } }
#define QUADa(MO) {                                                     \
    __builtin_amdgcn_s_setprio(1);                                      \
    _Pragma("unroll") for (int mi = 0; mi < 4; ++mi)                    \
    _Pragma("unroll") for (int ni = 0; ni < 2; ++ni) {                  \
      acc[MO + mi][ni] = MFMA16(AF[mi][0], Bf[ni][0], acc[MO + mi][ni]); \
      acc[MO + mi][ni] = MFMA16(AF[mi][1], Bf[ni][1], acc[MO + mi][ni]); } \
    __builtin_amdgcn_s_setprio(0); }
#define QUADb(MO) {                                                     \
    __builtin_amdgcn_s_setprio(1);                                      \
    _Pragma("unroll") for (int mi = 0; mi < 4; ++mi) {                  \
      acc[MO + mi][2] = MFMA16(AF[mi][0], Bf[2][0], acc[MO + mi][2]);   \
      acc[MO + mi][2] = MFMA16(AF[mi][1], Bf[2][1], acc[MO + mi][2]); } \
    __builtin_amdgcn_s_setprio(0); }

  STG_B3(0, 0); STG_B3(0, 1); STG_B3(0, 2); STG_A(0, 0); STG_A(0, 1);
  STG_B3(1, 0); STG_B3(1, 1); STG_B3(1, 2); STG_A(1, 0);
  VMC5;
  BAR;

  for (int i = 0; i < 8; ++i) {
    bool s = (i < 7);
    int k0t = 2 * i, k1t = 2 * i + 1;
    LDA(0, 0); LDB(0);
    STG_A(k1t, 1);
    BAR; QUADa(0); BAR;
    if (s) { STG_B3(k0t + 2, 0); STG_B3(k0t + 2, 1); }
    BAR; QUADb(0); BAR;
    LDA(0, 4096);
    if (s) STG_B3(k0t + 2, 2);
    BAR; QUADa(4); BAR;
    if (s) STG_A(k0t + 2, 0);
    if (i == 7) { VMC0; } else { VMC5; }
    BAR; QUADb(4); BAR;
    LDA(1, 0); LDB(1);
    if (s) STG_A(k0t + 2, 1);
    BAR; QUADa(0); BAR;
    if (s) { STG_B3(k1t + 2, 0); STG_B3(k1t + 2, 1); }
    BAR; QUADb(0); BAR;
    LDA(1, 4096);
    if (s) STG_B3(k1t + 2, 2);
    BAR; QUADa(4); BAR;
    if (s) STG_A(k1t + 2, 0);
    VMC5;
    BAR; QUADb(4); BAR;
  }
#undef STG_A
#undef STG_B3
#undef LDA
#undef LDB
#undef QUADa
#undef QUADb

#pragma unroll
  for (int ni = 0; ni < 3; ++ni) {
    int cb = n0 + wcn * 48 + ni * 16;
    if (cb < 2048) {
      float qs = (cb < 1024) ? qscale : 1.0f;
#pragma unroll
      for (int mi = 0; mi < 8; ++mi)
#pragma unroll
        for (int rg = 0; rg < 4; ++rg) {
          int row = m0 + wr * 128 + mi * 16 + lg * 4 + rg;
          int col = cb + lr;
          qkv[(size_t)row * 3072 + col] = f2bf((acc[mi][ni][rg] + bias[col]) * qs);
        }
    }
  }
  int gvs = 32 - 3 * bx;
  if (gvs < 0) gvs = 0;
  int b = by >> 3, sbase = (by & 7) * 256;
  u16* Vl = smem;
#pragma unroll
  for (int g = 0; g < 3; ++g) {
    if (g < gvs) continue;
    __syncthreads();
#pragma unroll
    for (int ni = 0; ni < 3; ++ni) {
      int blk = 3 * wcn + ni;
      if (blk >= 4 * g && blk < 4 * g + 4) {
        int d = (blk - 4 * g) * 16 + lr;
        int col = n0 + blk * 16 + lr;
#pragma unroll
        for (int mi = 0; mi < 8; ++mi) {
          int srow = wr * 128 + mi * 16 + lg * 4;
          union { u16 u[4]; unsigned long long q; } pk;
#pragma unroll
          for (int rg = 0; rg < 4; ++rg)
            pk.u[rg] = f2bf(acc[mi][ni][rg] + bias[col]);
          *(unsigned long long*)&Vl[d * 272 + srow] = pk.q;
        }
      }
    }
    __syncthreads();
    int hv = 3 * bx + g - 32;
    int d = t >> 3, sc = (t & 7) * 32;
    u16* dst = Vt + ((size_t)((b * 16 + hv) * 64 + d)) * 2048 + sbase + sc;
    const u16* src = Vl + d * 272 + sc;
#pragma unroll
    for (int j = 0; j < 4; ++j)
      *(uint4*)(dst + j * 8) = *(const uint4*)(src + j * 8);
  }
}

// ------------- GEMM2: 64x128 tile, 4 waves of 64x32, 2-phase dbuf -----------
__global__ __launch_bounds__(256) void gemm_bt64(const u16* __restrict__ A,
                                                 const u16* __restrict__ Bt,
                                                 const float* __restrict__ bias,
                                                 float* __restrict__ C,
                                                 int N, int K) {
  __shared__ __align__(16) u16 smem[2][6144];   // [buf][As 2048 | Bs 4096]
  int t = threadIdx.x;
  int w = t >> 6, l = t & 63;
  int lr = l & 15, lg = l >> 4;

  int nwg = gridDim.x * gridDim.y;
  int bid = blockIdx.y * gridDim.x + blockIdx.x;
  int orig = (bid & 7) * (nwg >> 3) + (bid >> 3);   // XCD-chunked remap
  int bx = orig % gridDim.x, by = orig / gridDim.x;
  int m0 = by * 64, n0 = bx * 128;

  f32x4 acc[4][2];
#pragma unroll
  for (int i = 0; i < 4; ++i)
#pragma unroll
    for (int j = 0; j < 2; ++j)
      acc[i][j] = f32x4{0.f, 0.f, 0.f, 0.f};

  int ra = w * 16 + (l >> 2);
  int ca = (l & 3) ^ ((ra >> 1) & 3);
  int rb1 = ra + 64;
  int cb1 = (l & 3) ^ ((rb1 >> 1) & 3);
  const u16* gA  = A  + (size_t)(m0 + ra) * K + ca * 8;
  const u16* gB0 = Bt + (size_t)(n0 + ra) * K + ca * 8;
  const u16* gB1 = Bt + (size_t)(n0 + rb1) * K + cb1 * 8;
  int oA  = (w * 16) * 32;
  int oB0 = 2048 + (w * 16) * 32;
  int oB1 = 2048 + (64 + w * 16) * 32;

#define STAGE(K0, BUF) {                                   \
    gload_lds16(gA + (K0), &smem[BUF][oA]);                \
    gload_lds16(gB0 + (K0), &smem[BUF][oB0]);              \
    gload_lds16(gB1 + (K0), &smem[BUF][oB1]);              }

  STAGE(0, 0);
  __syncthreads();
  int cur = 0;
  for (int k0 = 0; k0 < K; k0 += 32) {
    if (k0 + 32 < K) STAGE(k0 + 32, cur ^ 1);
    const u16* As = smem[cur];
    const u16* Bs = smem[cur] + 2048;
    bf16x8 af[4], bfr[2];
#pragma unroll
    for (int mi = 0; mi < 4; ++mi) {
      int row = mi * 16 + lr;
      af[mi] = *(const bf16x8*)(As + row * 32 + ((lg ^ ((row >> 1) & 3)) << 3));
    }
#pragma unroll
    for (int ni = 0; ni < 2; ++ni) {
      int row = w * 32 + ni * 16 + lr;
      bfr[ni] = *(const bf16x8*)(Bs + row * 32 + ((lg ^ ((row >> 1) & 3)) << 3));
    }
    __builtin_amdgcn_s_setprio(1);
#pragma unroll
    for (int mi = 0; mi < 4; ++mi)
#pragma unroll
      for (int ni = 0; ni < 2; ++ni)
        acc[mi][ni] = MFMA16(af[mi], bfr[ni], acc[mi][ni]);
    __builtin_amdgcn_s_setprio(0);
    __syncthreads();
    cur ^= 1;
  }
#undef STAGE

#pragma unroll
  for (int mi = 0; mi < 4; ++mi)
#pragma unroll
    for (int ni = 0; ni < 2; ++ni)
#pragma unroll
      for (int rg = 0; rg < 4; ++rg) {
        int row = m0 + mi * 16 + lg * 4 + rg;
        int col = n0 + w * 32 + ni * 16 + lr;
        C[(size_t)row * N + col] = acc[mi][ni][rg] + bias[col];
      }
}

// ======== attention tile (swapped QK^T -> C[k][q], log2 domain, no-max) =====
__device__ __forceinline__ void attn_tile(const u16* Ks, const u16* Vs,
                                          bf16x8 q0, bf16x8 q1, f32x4* o,
                                          float& l_run, bool diag,
                                          int w, int l, int lr, int lg) {
  f32x4 s[4];
  __builtin_amdgcn_s_setprio(1);
#pragma unroll
  for (int ct = 0; ct < 4; ++ct) {
    int row = ct * 16 + lr;
    bf16x8 kf0 = *(const bf16x8*)(Ks + ((row * 64 + lg * 8) ^ ((row & 7) << 3)));
    bf16x8 kf1 = *(const bf16x8*)(Ks + ((row * 64 + 32 + lg * 8) ^ ((row & 7) << 3)));
    f32x4 z = f32x4{0.f, 0.f, 0.f, 0.f};
    z = MFMA16(kf0, q0, z);
    z = MFMA16(kf1, q1, z);
    s[ct] = z;
  }
  __builtin_amdgcn_s_setprio(0);
  if (diag) {
    int qrel = w * 16 + lr;
#pragma unroll
    for (int ct = 0; ct < 4; ++ct)
#pragma unroll
      for (int rg = 0; rg < 4; ++rg)
        if ((ct * 16 + lg * 4 + rg) > qrel) s[ct][rg] = -1e30f;
  }
  float ps = 0.f;
#pragma unroll
  for (int ct = 0; ct < 4; ++ct)
#pragma unroll
    for (int rg = 0; rg < 4; ++rg) {
      float p = fexp2(s[ct][rg]);
      s[ct][rg] = p;
      ps += p;
    }
  l_run += sum_lg(ps);

  unsigned W00 = cvtpk_bf16(s[0][0], s[0][1]);
  unsigned W01 = cvtpk_bf16(s[0][2], s[0][3]);
  unsigned W10 = cvtpk_bf16(s[1][0], s[1][1]);
  unsigned W11 = cvtpk_bf16(s[1][2], s[1][3]);
  unsigned W20 = cvtpk_bf16(s[2][0], s[2][1]);
  unsigned W21 = cvtpk_bf16(s[2][2], s[2][3]);
  unsigned W30 = cvtpk_bf16(s[3][0], s[3][1]);
  unsigned W31 = cvtpk_bf16(s[3][2], s[3][3]);
  SWAP32(W00, W10); SWAP16(W00, W10);
  SWAP32(W01, W11); SWAP16(W01, W11);
  SWAP32(W20, W30); SWAP16(W20, W30);
  SWAP32(W21, W31); SWAP16(W21, W31);
  union { unsigned u[4]; bf16x8 v; } P0, P1;
  P0.u[0] = W00; P0.u[1] = W01; P0.u[2] = W10; P0.u[3] = W11;
  P1.u[0] = W20; P1.u[1] = W21; P1.u[2] = W30; P1.u[3] = W31;

  __builtin_amdgcn_s_setprio(1);
#pragma unroll
  for (int dt = 0; dt < 4; ++dt) {
    int row = dt * 16 + lr;
    bf16x8 vf0 = *(const bf16x8*)(Vs + ((row * 64 + lg * 8) ^ ((row & 7) << 3)));
    bf16x8 vf1 = *(const bf16x8*)(Vs + ((row * 64 + 32 + lg * 8) ^ ((row & 7) << 3)));
    o[dt] = MFMA16(P0.v, vf0, o[dt]);
    o[dt] = MFMA16(P1.v, vf1, o[dt]);
  }
  __builtin_amdgcn_s_setprio(0);
}

// ---------------- flash attention, causal, paired q-tiles, KV-SPLIT ----------
__global__ __launch_bounds__(256, 4) void attn_kernel(const u16* __restrict__ qkv,
                                                      const u16* __restrict__ Vt,
                                                      u16* __restrict__ po0,
                                                      u16* __restrict__ po1,
                                                      float* __restrict__ pl) {
  __shared__ __align__(16) u16 Ks[2][64 * 64];
  __shared__ __align__(16) u16 Vs[2][64 * 64];
  int bid = blockIdx.y * 32 + blockIdx.x;
  int orig = (bid & 7) * 128 + (bid >> 3);   // XCD chunk: 4 bh per XCD
  int half = orig & 1;
  int qtA = (orig >> 1) & 15;
  int bh = orig >> 5;
  int qtB = 31 - qtA;
  int m = (qtA >= 8) ? 8 : (15 - qtA);       // split point: 16/17 units each
  int kts = half ? m : 0;
  int kte = half ? (qtB + 1) : m;
  int b = bh >> 4, h = bh & 15;
  int t = threadIdx.x, w = t >> 6, l = t & 63;
  int lr = l & 15, lg = l >> 4;

  const u16* qbase = qkv + (size_t)b * S_LEN * 3072 + h * 64;
  int qrA = qtA * 64 + w * 16 + lr;
  int qrB = qtB * 64 + w * 16 + lr;
  bf16x8 qA0 = *(const bf16x8*)(qbase + (size_t)qrA * 3072 + lg * 8);
  bf16x8 qA1 = *(const bf16x8*)(qbase + (size_t)qrA * 3072 + 32 + lg * 8);
  bf16x8 qB0 = *(const bf16x8*)(qbase + (size_t)qrB * 3072 + lg * 8);
  bf16x8 qB1 = *(const bf16x8*)(qbase + (size_t)qrB * 3072 + 32 + lg * 8);

  f32x4 oA[4], oB[4];
#pragma unroll
  for (int i = 0; i < 4; ++i) { oA[i] = f32x4{0.f,0.f,0.f,0.f}; oB[i] = f32x4{0.f,0.f,0.f,0.f}; }
  float lA = 0.f, lB = 0.f;

  int r0s = t >> 3, r1s = r0s + 32;
  int soff = (t & 7) * 8;
  int e0 = (r0s * 64 + soff) ^ ((r0s & 7) << 3);
  int e1 = (r1s * 64 + soff) ^ ((r1s & 7) << 3);
  const u16* Kg = qkv + (size_t)b * S_LEN * 3072 + 1024 + h * 64 + soff;
  const u16* Vg = Vt + (size_t)bh * 64 * S_LEN + soff;

  uint4 k0r, k1r, v0r, v1r;
#define ISSUE(KT) {                                                     \
    int kk0 = (KT) * 64;                                                \
    k0r = *(const uint4*)(Kg + (size_t)(kk0 + r0s) * 3072);             \
    k1r = *(const uint4*)(Kg + (size_t)(kk0 + r1s) * 3072);             \
    v0r = *(const uint4*)(Vg + (size_t)r0s * S_LEN + kk0);              \
    v1r = *(const uint4*)(Vg + (size_t)r1s * S_LEN + kk0);              }

  ISSUE(kts);
  *(uint4*)(Ks[0] + e0) = k0r;
  *(uint4*)(Ks[0] + e1) = k1r;
  *(uint4*)(Vs[0] + e0) = v0r;
  *(uint4*)(Vs[0] + e1) = v1r;
  if (kts + 1 < kte) ISSUE(kts + 1);
  __syncthreads();

  int cur = 0;
  for (int kt = kts; kt < kte; ++kt) {
    if (kt + 1 < kte) {
      u16* Kd = Ks[cur ^ 1];
      u16* Vd = Vs[cur ^ 1];
      *(uint4*)(Kd + e0) = k0r;
      *(uint4*)(Kd + e1) = k1r;
      *(uint4*)(Vd + e0) = v0r;
      *(uint4*)(Vd + e1) = v1r;
    }
    if (kt + 2 < kte) ISSUE(kt + 2);
    const u16* Kc = Ks[cur];
    const u16* Vc = Vs[cur];
    if (kt <= qtA)
      attn_tile(Kc, Vc, qA0, qA1, oA, lA, kt == qtA, w, l, lr, lg);
    attn_tile(Kc, Vc, qB0, qB1, oB, lB, kt == qtB, w, l, lr, lg);
    __syncthreads();
    cur ^= 1;
  }
#undef ISSUE

  u16* po = half ? po1 : po0;
  float* plh = pl + half * 65536;
#pragma unroll
  for (int dt = 0; dt < 4; ++dt)
#pragma unroll
    for (int rg = 0; rg < 4; ++rg) {
      int d = dt * 16 + lr;
      int qA_ = qtA * 64 + w * 16 + lg * 4 + rg;
      int qB_ = qtB * 64 + w * 16 + lg * 4 + rg;
      po[(size_t)(b * S_LEN + qA_) * 1024 + h * 64 + d] = f2bf(oA[dt][rg]);
      po[(size_t)(b * S_LEN + qB_) * 1024 + h * 64 + d] = f2bf(oB[dt][rg]);
    }
  if (lg == 0) {
    plh[bh * 2048 + qtA * 64 + w * 16 + lr] = lA;
    plh[bh * 2048 + qtB * 64 + w * 16 + lr] = lB;
  }
}

// ---------------- combine: out = (po0 + po1) * rcp(l0 + l1) -----------------
__global__ __launch_bounds__(256) void attn_combine(const u16* po0,
                                                    const u16* __restrict__ po1,
                                                    const float* __restrict__ pl,
                                                    u16* out) {
  int i = (blockIdx.x * 256 + threadIdx.x) * 8;
  int row = i >> 10;                 // b*2048 + q
  int h = (i & 1023) >> 6;
  int bh = (row >> 11) * 16 + h;
  int q = row & 2047;
  float r = frcp(pl[bh * 2048 + q] + pl[65536 + bh * 2048 + q]);
  bf16x8 a = *(const bf16x8*)(po0 + i);
  bf16x8 c = *(const bf16x8*)(po1 + i);
  union { u16 u[8]; bf16x8 v; } o;
#pragma unroll
  for (int j = 0; j < 8; ++j)
    o.u[j] = f2bf((bf2f((u16)a[j]) + bf2f((u16)c[j])) * r);
  *(bf16x8*)(out + i) = o.v;
}

// ---------------- launcher ----------------
extern "C" void kernel_launch(void* const* d_in, const int* in_sizes, int n_in,
                              void* d_out, int out_size, void* d_ws, size_t ws_size,
                              hipStream_t stream) {
  const float* x     = (const float*)d_in[0];
  const float* w_qkv = (const float*)d_in[1];
  const float* b_qkv = (const float*)d_in[2];
  const float* w_out = (const float*)d_in[3];
  const float* b_out = (const float*)d_in[4];
  float* out = (float*)d_out;

  // ws layout (56 MB) with liveness-based aliasing:
  //  0-8   : x_bf (dead after gemm1)  / po1
  //  8-14  : wqkvT (dead after gemm1) / pl (512 KB)
  //  14-16 : woutT (live until gemm2)
  //  16-40 : qkv (V third unused — V goes straight to Vt)
  //  40-48 : Vt
  //  48-56 : po0 / attnb (combine output aliases po0)
  char* ws = (char*)d_ws;
  u16* x_bf   = (u16*)(ws);
  u16* po1    = (u16*)(ws);
  u16* wqkvT  = (u16*)(ws + ( 8ull << 20));
  float* pl   = (float*)(ws + ( 8ull << 20));
  u16* woutT  = (u16*)(ws + (14ull << 20));
  u16* qkv    = (u16*)(ws + (16ull << 20));
  u16* Vt     = (u16*)(ws + (40ull << 20));
  u16* po0    = (u16*)(ws + (48ull << 20));
  u16* attnb  = (u16*)(ws + (48ull << 20));

  prep<<<2048 + 1024, 256, 0, stream>>>(x, w_qkv, w_out, x_bf, wqkvT, woutT);
  gemm_qkv<<<dim3(16, 16), 512, 0, stream>>>(x_bf, wqkvT, b_qkv, qkv, Vt,
                                             LOG2E_DIV8);
  attn_kernel<<<dim3(32, 32), 256, 0, stream>>>(qkv, Vt, po0, po1, pl);
  attn_combine<<<MTOT * 1024 / (256 * 8), 256, 0, stream>>>(po0, po1, pl, attnb);
  gemm_bt64<<<dim3(8, 64), 256, 0, stream>>>(attnb, woutT, b_out, out, 1024, 1024);
}

// Round 18
// 99.920 us; speedup vs baseline: 1.0809x; 1.0129x over previous
//
#include <hip/hip_runtime.h>

typedef unsigned short u16;
typedef __attribute__((ext_vector_type(8))) short bf16x8;
typedef __attribute__((ext_vector_type(4))) float f32x4;

#define S_LEN 2048
#define MTOT  4096   // B*S
#define LOG2E_DIV8 0.1803368784f   // 0.125 * log2(e)

__device__ inline u16 f2bf(float f) {
  union { float f; unsigned u; } x; x.f = f;
  unsigned r = x.u + 0x7fffu + ((x.u >> 16) & 1u);
  return (u16)(r >> 16);
}
__device__ inline float bf2f(u16 u) {
  union { unsigned u; float f; } x; x.u = ((unsigned)u) << 16;
  return x.f;
}

__device__ __forceinline__ unsigned cvtpk_bf16(float lo, float hi) {
  unsigned r;
  asm("v_cvt_pk_bf16_f32 %0, %1, %2" : "=v"(r) : "v"(lo), "v"(hi));
  return r;
}
__device__ __forceinline__ float fexp2(float x) {
  float r;
  asm("v_exp_f32 %0, %1" : "=v"(r) : "v"(x));
  return r;
}
__device__ __forceinline__ float frcp(float x) {
  float r;
  asm("v_rcp_f32 %0, %1" : "=v"(r) : "v"(x));
  return r;
}

// --- gfx950 permlane swaps (both operands updated) ---
#define SWAP32(a, b) asm("v_permlane32_swap_b32 %0, %1" : "+v"(a), "+v"(b))
#define SWAP16(a, b) asm("v_permlane16_swap_b32 %0, %1" : "+v"(a), "+v"(b))

// sum of x over the 4 row-groups (lane bits 4-5), result in every lane
__device__ __forceinline__ float sum_lg(float x) {
  float a = x, b = x;
  SWAP32(a, b);
  float s = a + b;
  float c = s, d = s;
  SWAP16(c, d);
  return c + d;
}

typedef __attribute__((address_space(1))) const unsigned int gu32;
typedef __attribute__((address_space(3))) unsigned int lu32;
__device__ __forceinline__ void gload_lds16(const void* g, void* l) {
  __builtin_amdgcn_global_load_lds((gu32*)g, (lu32*)l, 16, 0, 0);
}

#define MFMA16(a, b, c) __builtin_amdgcn_mfma_f32_16x16x32_bf16((a), (b), (c), 0, 0, 0)
#define BAR  __builtin_amdgcn_s_barrier()
#define VMC5 asm volatile("s_waitcnt vmcnt(5)" ::: "memory")
#define VMC0 asm volatile("s_waitcnt vmcnt(0)" ::: "memory")

// ---- prep: x cast (blocks 0..2047, 8 f32/thread) + weight transpose --------
__global__ __launch_bounds__(256) void prep(const float* __restrict__ x,
                                            const float* __restrict__ wqkv,
                                            const float* __restrict__ wout,
                                            u16* __restrict__ x_bf,
                                            u16* __restrict__ dqkv,
                                            u16* __restrict__ dwout) {
  __shared__ float tile[64][65];
  int bid = blockIdx.x;
  int t = threadIdx.x;
  if (bid < 2048) {
    int i = (bid * 256 + t) * 8;
    float4 v0 = *(const float4*)(x + i);
    float4 v1 = *(const float4*)(x + i + 4);
    union { u16 u[8]; uint4 q; } o;
    o.u[0] = f2bf(v0.x); o.u[1] = f2bf(v0.y); o.u[2] = f2bf(v0.z); o.u[3] = f2bf(v0.w);
    o.u[4] = f2bf(v1.x); o.u[5] = f2bf(v1.y); o.u[6] = f2bf(v1.z); o.u[7] = f2bf(v1.w);
    *(uint4*)(x_bf + i) = o.q;
    return;
  }
  int idx = bid - 2048;
  int bx = idx & 63, by = idx >> 6;
  const float* src; u16* dst; int N, n0;
  if (bx < 48) { src = wqkv; dst = dqkv; N = 3072; n0 = bx * 64; }
  else         { src = wout; dst = dwout; N = 1024; n0 = (bx - 48) * 64; }
  int K = 1024, k0 = by * 64;
  for (int i = 0; i < 16; ++i) {
    int id2 = t + 256 * i;
    int r = id2 >> 6, c = id2 & 63;
    tile[r][c] = src[(size_t)(k0 + r) * N + n0 + c];
  }
  __syncthreads();
  for (int i = 0; i < 16; ++i) {
    int id2 = t + 256 * i;
    int r = id2 >> 6, c = id2 & 63;
    dst[(size_t)(n0 + r) * K + k0 + c] = f2bf(tile[c][r]);
  }
}

// ---- GEMM1 (QKV): 256x192 tile, BK=64, 8 waves, 8-phase counted-vmcnt ------
__global__ __launch_bounds__(512, 1) void gemm_qkv(const u16* __restrict__ A,
                                                   const u16* __restrict__ Bt,
                                                   const float* __restrict__ bias,
                                                   u16* __restrict__ qkv,
                                                   u16* __restrict__ Vt,
                                                   float qscale) {
  __shared__ __align__(16) u16 smem[57344];   // A: [0,32768) ; B: [32768,57344)
  int t = threadIdx.x;
  int w = t >> 6, l = t & 63;
  int wr = w >> 2, wcn = w & 3;       // wave grid 2(M) x 4(N), per-wave 128x48
  int lr = l & 15, lg = l >> 4;

  int bid = blockIdx.y * 16 + blockIdx.x;
  int orig = (bid & 7) * 32 + (bid >> 3);    // XCD-chunked remap (256 % 8 == 0)
  int bx = orig & 15, by = orig >> 4;
  int m0 = by * 256, n0 = bx * 192;

  f32x4 acc[8][3];
#pragma unroll
  for (int i = 0; i < 8; ++i)
#pragma unroll
    for (int j = 0; j < 3; ++j)
      acc[i][j] = f32x4{0.f, 0.f, 0.f, 0.f};

  int cg = ((t & 7) ^ ((t >> 3) & 7)) * 8;
  const u16* gAh[2][2];
  const u16* gB3[3];
#pragma unroll
  for (int h = 0; h < 2; ++h)
#pragma unroll
    for (int j = 0; j < 2; ++j)
      gAh[h][j] = A + (size_t)(m0 + h * 128 + j * 64 + (t >> 3)) * 1024 + cg;
#pragma unroll
  for (int th = 0; th < 3; ++th)
    gB3[th] = Bt + (size_t)(n0 + th * 64 + (t >> 3)) * 1024 + cg;

#define STG_A(kt, h) {                                                  \
    u16* d_ = smem + (((kt) & 1) * 2 + (h)) * 8192 + t * 8;             \
    gload_lds16(gAh[h][0] + (size_t)(kt) * 64, d_);                     \
    gload_lds16(gAh[h][1] + (size_t)(kt) * 64, d_ + 4096);              }
#define STG_B3(kt, th) {                                                \
    u16* d_ = smem + 32768 + (((kt) & 1) * 3 + (th)) * 4096 + t * 8;    \
    gload_lds16(gB3[th] + (size_t)(kt) * 64, d_);                       }

  int co0 = (lg ^ (lr & 7)) << 3;
  int co1 = ((4 + lg) ^ (lr & 7)) << 3;
  const u16* bA[2] = { smem + wr * 8192, smem + (2 + wr) * 8192 };
  const u16* bB[2] = { smem + 32768, smem + 32768 + 12288 };
  int rB = (48 * wcn + lr) * 64;

  bf16x8 AF[4][2], Bf[3][2];
#define LDA(B_, OFF) { const u16* p_ = bA[B_] + (OFF) + lr * 64;        \
    _Pragma("unroll") for (int mi = 0; mi < 4; ++mi) {                  \
      AF[mi][0] = *(const bf16x8*)(p_ + mi * 1024 + co0);               \
      AF[mi][1] = *(const bf16x8*)(p_ + mi * 1024 + co1); } }
#define LDB(B_) { const u16* p_ = bB[B_] + rB;                          \
    _Pragma("unroll") for (int ni = 0; ni < 3; ++ni) {                  \
      Bf[ni][0] = *(const bf16x8*)(p_ + ni * 1024 + co0);               \
      Bf[ni][1] = *(const bf16x8*)(p_ + ni * 1024 + co1); } }
#define QUADa(MO) {                                                     \
    __builtin_amdgcn_s_setprio(1);                                      \
    _Pragma("unroll") for (int mi = 0; mi < 4; ++mi)                    \
    _Pragma("unroll") for (int ni = 0; ni < 2; ++ni) {                  \
      acc[MO + mi][ni] = MFMA16(AF[mi][0], Bf[ni][0], acc[MO + mi][ni]); \
      acc[MO + mi][ni] = MFMA16(AF[mi][1], Bf[ni][1], acc[MO + mi][ni]); } \
    __builtin_amdgcn_s_setprio(0); }
#define QUADb(MO) {                                                     \
    __builtin_amdgcn_s_setprio(1);                                      \
    _Pragma("unroll") for (int mi = 0; mi < 4; ++mi) {                  \
      acc[MO + mi][2] = MFMA16(AF[mi][0], Bf[2][0], acc[MO + mi][2]);   \
      acc[MO + mi][2] = MFMA16(AF[mi][1], Bf[2][1], acc[MO + mi][2]); } \
    __builtin_amdgcn_s_setprio(0); }

  STG_B3(0, 0); STG_B3(0, 1); STG_B3(0, 2); STG_A(0, 0); STG_A(0, 1);
  STG_B3(1, 0); STG_B3(1, 1); STG_B3(1, 2); STG_A(1, 0);
  VMC5;
  BAR;

  for (int i = 0; i < 8; ++i) {
    bool s = (i < 7);
    int k0t = 2 * i, k1t = 2 * i + 1;
    LDA(0, 0); LDB(0);
    STG_A(k1t, 1);
    BAR; QUADa(0); BAR;
    if (s) { STG_B3(k0t + 2, 0); STG_B3(k0t + 2, 1); }
    BAR; QUADb(0); BAR;
    LDA(0, 4096);
    if (s) STG_B3(k0t + 2, 2);
    BAR; QUADa(4); BAR;
    if (s) STG_A(k0t + 2, 0);
    if (i == 7) { VMC0; } else { VMC5; }
    BAR; QUADb(4); BAR;
    LDA(1, 0); LDB(1);
    if (s) STG_A(k0t + 2, 1);
    BAR; QUADa(0); BAR;
    if (s) { STG_B3(k1t + 2, 0); STG_B3(k1t + 2, 1); }
    BAR; QUADb(0); BAR;
    LDA(1, 4096);
    if (s) STG_B3(k1t + 2, 2);
    BAR; QUADa(4); BAR;
    if (s) STG_A(k1t + 2, 0);
    VMC5;
    BAR; QUADb(4); BAR;
  }
#undef STG_A
#undef STG_B3
#undef LDA
#undef LDB
#undef QUADa
#undef QUADb

#pragma unroll
  for (int ni = 0; ni < 3; ++ni) {
    int cb = n0 + wcn * 48 + ni * 16;
    if (cb < 2048) {
      float qs = (cb < 1024) ? qscale : 1.0f;
#pragma unroll
      for (int mi = 0; mi < 8; ++mi)
#pragma unroll
        for (int rg = 0; rg < 4; ++rg) {
          int row = m0 + wr * 128 + mi * 16 + lg * 4 + rg;
          int col = cb + lr;
          qkv[(size_t)row * 3072 + col] = f2bf((acc[mi][ni][rg] + bias[col]) * qs);
        }
    }
  }
  int gvs = 32 - 3 * bx;
  if (gvs < 0) gvs = 0;
  int b = by >> 3, sbase = (by & 7) * 256;
  u16* Vl = smem;
#pragma unroll
  for (int g = 0; g < 3; ++g) {
    if (g < gvs) continue;
    __syncthreads();
#pragma unroll
    for (int ni = 0; ni < 3; ++ni) {
      int blk = 3 * wcn + ni;
      if (blk >= 4 * g && blk < 4 * g + 4) {
        int d = (blk - 4 * g) * 16 + lr;
        int col = n0 + blk * 16 + lr;
#pragma unroll
        for (int mi = 0; mi < 8; ++mi) {
          int srow = wr * 128 + mi * 16 + lg * 4;
          union { u16 u[4]; unsigned long long q; } pk;
#pragma unroll
          for (int rg = 0; rg < 4; ++rg)
            pk.u[rg] = f2bf(acc[mi][ni][rg] + bias[col]);
          *(unsigned long long*)&Vl[d * 272 + srow] = pk.q;
        }
      }
    }
    __syncthreads();
    int hv = 3 * bx + g - 32;
    int d = t >> 3, sc = (t & 7) * 32;
    u16* dst = Vt + ((size_t)((b * 16 + hv) * 64 + d)) * 2048 + sbase + sc;
    const u16* src = Vl + d * 272 + sc;
#pragma unroll
    for (int j = 0; j < 4; ++j)
      *(uint4*)(dst + j * 8) = *(const uint4*)(src + j * 8);
  }
}

// ------------- GEMM2: 64x128 tile, 4 waves of 64x32, 2-phase dbuf -----------
__global__ __launch_bounds__(256) void gemm_bt64(const u16* __restrict__ A,
                                                 const u16* __restrict__ Bt,
                                                 const float* __restrict__ bias,
                                                 float* __restrict__ C,
                                                 int N, int K) {
  __shared__ __align__(16) u16 smem[2][6144];   // [buf][As 2048 | Bs 4096]
  int t = threadIdx.x;
  int w = t >> 6, l = t & 63;
  int lr = l & 15, lg = l >> 4;

  int nwg = gridDim.x * gridDim.y;
  int bid = blockIdx.y * gridDim.x + blockIdx.x;
  int orig = (bid & 7) * (nwg >> 3) + (bid >> 3);   // XCD-chunked remap
  int bx = orig % gridDim.x, by = orig / gridDim.x;
  int m0 = by * 64, n0 = bx * 128;

  f32x4 acc[4][2];
#pragma unroll
  for (int i = 0; i < 4; ++i)
#pragma unroll
    for (int j = 0; j < 2; ++j)
      acc[i][j] = f32x4{0.f, 0.f, 0.f, 0.f};

  int ra = w * 16 + (l >> 2);
  int ca = (l & 3) ^ ((ra >> 1) & 3);
  int rb1 = ra + 64;
  int cb1 = (l & 3) ^ ((rb1 >> 1) & 3);
  const u16* gA  = A  + (size_t)(m0 + ra) * K + ca * 8;
  const u16* gB0 = Bt + (size_t)(n0 + ra) * K + ca * 8;
  const u16* gB1 = Bt + (size_t)(n0 + rb1) * K + cb1 * 8;
  int oA  = (w * 16) * 32;
  int oB0 = 2048 + (w * 16) * 32;
  int oB1 = 2048 + (64 + w * 16) * 32;

#define STAGE(K0, BUF) {                                   \
    gload_lds16(gA + (K0), &smem[BUF][oA]);                \
    gload_lds16(gB0 + (K0), &smem[BUF][oB0]);              \
    gload_lds16(gB1 + (K0), &smem[BUF][oB1]);              }

  STAGE(0, 0);
  __syncthreads();
  int cur = 0;
  for (int k0 = 0; k0 < K; k0 += 32) {
    if (k0 + 32 < K) STAGE(k0 + 32, cur ^ 1);
    const u16* As = smem[cur];
    const u16* Bs = smem[cur] + 2048;
    bf16x8 af[4], bfr[2];
#pragma unroll
    for (int mi = 0; mi < 4; ++mi) {
      int row = mi * 16 + lr;
      af[mi] = *(const bf16x8*)(As + row * 32 + ((lg ^ ((row >> 1) & 3)) << 3));
    }
#pragma unroll
    for (int ni = 0; ni < 2; ++ni) {
      int row = w * 32 + ni * 16 + lr;
      bfr[ni] = *(const bf16x8*)(Bs + row * 32 + ((lg ^ ((row >> 1) & 3)) << 3));
    }
    __builtin_amdgcn_s_setprio(1);
#pragma unroll
    for (int mi = 0; mi < 4; ++mi)
#pragma unroll
      for (int ni = 0; ni < 2; ++ni)
        acc[mi][ni] = MFMA16(af[mi], bfr[ni], acc[mi][ni]);
    __builtin_amdgcn_s_setprio(0);
    __syncthreads();
    cur ^= 1;
  }
#undef STAGE

#pragma unroll
  for (int mi = 0; mi < 4; ++mi)
#pragma unroll
    for (int ni = 0; ni < 2; ++ni)
#pragma unroll
      for (int rg = 0; rg < 4; ++rg) {
        int row = m0 + mi * 16 + lg * 4 + rg;
        int col = n0 + w * 32 + ni * 16 + lr;
        C[(size_t)row * N + col] = acc[mi][ni][rg] + bias[col];
      }
}

// ======== attention tile (swapped QK^T -> C[k][q], log2 domain, no-max) =====
__device__ __forceinline__ void attn_tile(const u16* Ks, const u16* Vs,
                                          bf16x8 q0, bf16x8 q1, f32x4* o,
                                          float& l_run, bool diag,
                                          int w, int l, int lr, int lg) {
  f32x4 s[4];
  __builtin_amdgcn_s_setprio(1);
#pragma unroll
  for (int ct = 0; ct < 4; ++ct) {
    int row = ct * 16 + lr;
    bf16x8 kf0 = *(const bf16x8*)(Ks + ((row * 64 + lg * 8) ^ ((row & 7) << 3)));
    bf16x8 kf1 = *(const bf16x8*)(Ks + ((row * 64 + 32 + lg * 8) ^ ((row & 7) << 3)));
    f32x4 z = f32x4{0.f, 0.f, 0.f, 0.f};
    z = MFMA16(kf0, q0, z);
    z = MFMA16(kf1, q1, z);
    s[ct] = z;
  }
  __builtin_amdgcn_s_setprio(0);
  if (diag) {
    int qrel = w * 16 + lr;
#pragma unroll
    for (int ct = 0; ct < 4; ++ct)
#pragma unroll
      for (int rg = 0; rg < 4; ++rg)
        if ((ct * 16 + lg * 4 + rg) > qrel) s[ct][rg] = -1e30f;
  }
  float ps = 0.f;
#pragma unroll
  for (int ct = 0; ct < 4; ++ct)
#pragma unroll
    for (int rg = 0; rg < 4; ++rg) {
      float p = fexp2(s[ct][rg]);
      s[ct][rg] = p;
      ps += p;
    }
  l_run += sum_lg(ps);

  unsigned W00 = cvtpk_bf16(s[0][0], s[0][1]);
  unsigned W01 = cvtpk_bf16(s[0][2], s[0][3]);
  unsigned W10 = cvtpk_bf16(s[1][0], s[1][1]);
  unsigned W11 = cvtpk_bf16(s[1][2], s[1][3]);
  unsigned W20 = cvtpk_bf16(s[2][0], s[2][1]);
  unsigned W21 = cvtpk_bf16(s[2][2], s[2][3]);
  unsigned W30 = cvtpk_bf16(s[3][0], s[3][1]);
  unsigned W31 = cvtpk_bf16(s[3][2], s[3][3]);
  SWAP32(W00, W10); SWAP16(W00, W10);
  SWAP32(W01, W11); SWAP16(W01, W11);
  SWAP32(W20, W30); SWAP16(W20, W30);
  SWAP32(W21, W31); SWAP16(W21, W31);
  union { unsigned u[4]; bf16x8 v; } P0, P1;
  P0.u[0] = W00; P0.u[1] = W01; P0.u[2] = W10; P0.u[3] = W11;
  P1.u[0] = W20; P1.u[1] = W21; P1.u[2] = W30; P1.u[3] = W31;

  __builtin_amdgcn_s_setprio(1);
#pragma unroll
  for (int dt = 0; dt < 4; ++dt) {
    int row = dt * 16 + lr;
    bf16x8 vf0 = *(const bf16x8*)(Vs + ((row * 64 + lg * 8) ^ ((row & 7) << 3)));
    bf16x8 vf1 = *(const bf16x8*)(Vs + ((row * 64 + 32 + lg * 8) ^ ((row & 7) << 3)));
    o[dt] = MFMA16(P0.v, vf0, o[dt]);
    o[dt] = MFMA16(P1.v, vf1, o[dt]);
  }
  __builtin_amdgcn_s_setprio(0);
}

// ---------------- flash attention, causal, paired q-tiles, KV-SPLIT ----------
// Staging via global_load_lds (2-phase dbuf): linear LDS dest + inverse-
// swizzled global source reproduces the same swizzled layout the reads expect
// (both-sides rule). Solo compute path unchanged (proven).
__global__ __launch_bounds__(256, 4) void attn_kernel(const u16* __restrict__ qkv,
                                                      const u16* __restrict__ Vt,
                                                      u16* __restrict__ po0,
                                                      u16* __restrict__ po1,
                                                      float* __restrict__ pl) {
  __shared__ __align__(16) u16 Ks[2][64 * 64];
  __shared__ __align__(16) u16 Vs[2][64 * 64];
  int bid = blockIdx.y * 32 + blockIdx.x;
  int orig = (bid & 7) * 128 + (bid >> 3);   // XCD chunk: 4 bh per XCD
  int half = orig & 1;
  int qtA = (orig >> 1) & 15;
  int bh = orig >> 5;
  int qtB = 31 - qtA;
  int m = (qtA >= 8) ? 8 : (15 - qtA);       // split point: 16/17 units each
  int kts = half ? m : 0;
  int kte = half ? (qtB + 1) : m;
  int b = bh >> 4, h = bh & 15;
  int t = threadIdx.x, w = t >> 6, l = t & 63;
  int lr = l & 15, lg = l >> 4;

  const u16* qbase = qkv + (size_t)b * S_LEN * 3072 + h * 64;
  int qrA = qtA * 64 + w * 16 + lr;
  int qrB = qtB * 64 + w * 16 + lr;
  bf16x8 qA0 = *(const bf16x8*)(qbase + (size_t)qrA * 3072 + lg * 8);
  bf16x8 qA1 = *(const bf16x8*)(qbase + (size_t)qrA * 3072 + 32 + lg * 8);
  bf16x8 qB0 = *(const bf16x8*)(qbase + (size_t)qrB * 3072 + lg * 8);
  bf16x8 qB1 = *(const bf16x8*)(qbase + (size_t)qrB * 3072 + 32 + lg * 8);

  f32x4 oA[4], oB[4];
#pragma unroll
  for (int i = 0; i < 4; ++i) { oA[i] = f32x4{0.f,0.f,0.f,0.f}; oB[i] = f32x4{0.f,0.f,0.f,0.f}; }
  float lA = 0.f, lB = 0.f;

  // gload_lds staging: thread t covers rows r0 and r0+32, chunk (t&7);
  // source column pre-swizzled by row&7 ((r0+32)&7 == r0&7 -> same csw).
  int r0 = t >> 3;
  int csw = ((t & 7) ^ (r0 & 7)) * 8;
  const u16* Kg = qkv + (size_t)b * S_LEN * 3072 + 1024 + h * 64 + csw;
  const u16* Vg = Vt + (size_t)bh * 64 * S_LEN + csw;

#define STAGE(BUF, KT) {                                                 \
    int kk0 = (KT) * 64;                                                 \
    u16* kd = &Ks[BUF][0] + t * 8;                                       \
    u16* vd = &Vs[BUF][0] + t * 8;                                       \
    gload_lds16(Kg + (size_t)(kk0 + r0) * 3072, kd);                     \
    gload_lds16(Kg + (size_t)(kk0 + r0 + 32) * 3072, kd + 2048);         \
    gload_lds16(Vg + (size_t)r0 * S_LEN + kk0, vd);                      \
    gload_lds16(Vg + (size_t)(r0 + 32) * S_LEN + kk0, vd + 2048);        }

  STAGE(0, kts);
  __syncthreads();

  int cur = 0;
  for (int kt = kts; kt < kte; ++kt) {
    if (kt + 1 < kte) STAGE(cur ^ 1, kt + 1);   // DMA in flight during compute
    const u16* Kc = Ks[cur];
    const u16* Vc = Vs[cur];
    if (kt <= qtA)
      attn_tile(Kc, Vc, qA0, qA1, oA, lA, kt == qtA, w, l, lr, lg);
    attn_tile(Kc, Vc, qB0, qB1, oB, lB, kt == qtB, w, l, lr, lg);
    __syncthreads();   // drains vmcnt -> next buffer ready
    cur ^= 1;
  }
#undef STAGE

  u16* po = half ? po1 : po0;
  float* plh = pl + half * 65536;
#pragma unroll
  for (int dt = 0; dt < 4; ++dt)
#pragma unroll
    for (int rg = 0; rg < 4; ++rg) {
      int d = dt * 16 + lr;
      int qA_ = qtA * 64 + w * 16 + lg * 4 + rg;
      int qB_ = qtB * 64 + w * 16 + lg * 4 + rg;
      po[(size_t)(b * S_LEN + qA_) * 1024 + h * 64 + d] = f2bf(oA[dt][rg]);
      po[(size_t)(b * S_LEN + qB_) * 1024 + h * 64 + d] = f2bf(oB[dt][rg]);
    }
  if (lg == 0) {
    plh[bh * 2048 + qtA * 64 + w * 16 + lr] = lA;
    plh[bh * 2048 + qtB * 64 + w * 16 + lr] = lB;
  }
}

// ---------------- combine: out = (po0 + po1) * rcp(l0 + l1) -----------------
__global__ __launch_bounds__(256) void attn_combine(const u16* po0,
                                                    const u16* __restrict__ po1,
                                                    const float* __restrict__ pl,
                                                    u16* out) {
  int i = (blockIdx.x * 256 + threadIdx.x) * 8;
  int row = i >> 10;                 // b*2048 + q
  int h = (i & 1023) >> 6;
  int bh = (row >> 11) * 16 + h;
  int q = row & 2047;
  float r = frcp(pl[bh * 2048 + q] + pl[65536 + bh * 2048 + q]);
  bf16x8 a = *(const bf16x8*)(po0 + i);
  bf16x8 c = *(const bf16x8*)(po1 + i);
  union { u16 u[8]; bf16x8 v; } o;
#pragma unroll
  for (int j = 0; j < 8; ++j)
    o.u[j] = f2bf((bf2f((u16)a[j]) + bf2f((u16)c[j])) * r);
  *(bf16x8*)(out + i) = o.v;
}

// ---------------- launcher ----------------
extern "C" void kernel_launch(void* const* d_in, const int* in_sizes, int n_in,
                              void* d_out, int out_size, void* d_ws, size_t ws_size,
                              hipStream_t stream) {
  const float* x     = (const float*)d_in[0];
  const float* w_qkv = (const float*)d_in[1];
  const float* b_qkv = (const float*)d_in[2];
  const float* w_out = (const float*)d_in[3];
  const float* b_out = (const float*)d_in[4];
  float* out = (float*)d_out;

  // ws layout (56 MB) with liveness-based aliasing:
  //  0-8   : x_bf (dead after gemm1)  / po1
  //  8-14  : wqkvT (dead after gemm1) / pl (512 KB)
  //  14-16 : woutT (live until gemm2)
  //  16-40 : qkv (V third unused — V goes straight to Vt)
  //  40-48 : Vt
  //  48-56 : po0 / attnb (combine output aliases po0)
  char* ws = (char*)d_ws;
  u16* x_bf   = (u16*)(ws);
  u16* po1    = (u16*)(ws);
  u16* wqkvT  = (u16*)(ws + ( 8ull << 20));
  float* pl   = (float*)(ws + ( 8ull << 20));
  u16* woutT  = (u16*)(ws + (14ull << 20));
  u16* qkv    = (u16*)(ws + (16ull << 20));
  u16* Vt     = (u16*)(ws + (40ull << 20));
  u16* po0    = (u16*)(ws + (48ull << 20));
  u16* attnb  = (u16*)(ws + (48ull << 20));

  prep<<<2048 + 1024, 256, 0, stream>>>(x, w_qkv, w_out, x_bf, wqkvT, woutT);
  gemm_qkv<<<dim3(16, 16), 512, 0, stream>>>(x_bf, wqkvT, b_qkv, qkv, Vt,
                                             LOG2E_DIV8);
  attn_kernel<<<dim3(32, 32), 256, 0, stream>>>(qkv, Vt, po0, po1, pl);
  attn_combine<<<MTOT * 1024 / (256 * 8), 256, 0, stream>>>(po0, po1, pl, attnb);
  gemm_bt64<<<dim3(8, 64), 256, 0, stream>>>(attnb, woutT, b_out, out, 1024, 1024);
}

// Round 19
// 99.688 us; speedup vs baseline: 1.0834x; 1.0023x over previous
//
#include <hip/hip_runtime.h>

typedef unsigned short u16;
typedef __attribute__((ext_vector_type(8))) short bf16x8;
typedef __attribute__((ext_vector_type(4))) float f32x4;

#define S_LEN 2048
#define MTOT  4096   // B*S
#define LOG2E_DIV8 0.1803368784f   // 0.125 * log2(e)

__device__ inline u16 f2bf(float f) {
  union { float f; unsigned u; } x; x.f = f;
  unsigned r = x.u + 0x7fffu + ((x.u >> 16) & 1u);
  return (u16)(r >> 16);
}
__device__ inline float bf2f(u16 u) {
  union { unsigned u; float f; } x; x.u = ((unsigned)u) << 16;
  return x.f;
}

__device__ __forceinline__ unsigned cvtpk_bf16(float lo, float hi) {
  unsigned r;
  asm("v_cvt_pk_bf16_f32 %0, %1, %2" : "=v"(r) : "v"(lo), "v"(hi));
  return r;
}
__device__ __forceinline__ float fexp2(float x) {
  float r;
  asm("v_exp_f32 %0, %1" : "=v"(r) : "v"(x));
  return r;
}
__device__ __forceinline__ float frcp(float x) {
  float r;
  asm("v_rcp_f32 %0, %1" : "=v"(r) : "v"(x));
  return r;
}

// --- gfx950 permlane swaps (both operands updated) ---
#define SWAP32(a, b) asm("v_permlane32_swap_b32 %0, %1" : "+v"(a), "+v"(b))
#define SWAP16(a, b) asm("v_permlane16_swap_b32 %0, %1" : "+v"(a), "+v"(b))

// sum of x over the 4 row-groups (lane bits 4-5), result in every lane
__device__ __forceinline__ float sum_lg(float x) {
  float a = x, b = x;
  SWAP32(a, b);
  float s = a + b;
  float c = s, d = s;
  SWAP16(c, d);
  return c + d;
}

typedef __attribute__((address_space(1))) const unsigned int gu32;
typedef __attribute__((address_space(3))) unsigned int lu32;
__device__ __forceinline__ void gload_lds16(const void* g, void* l) {
  __builtin_amdgcn_global_load_lds((gu32*)g, (lu32*)l, 16, 0, 0);
}

#define MFMA16(a, b, c) __builtin_amdgcn_mfma_f32_16x16x32_bf16((a), (b), (c), 0, 0, 0)
#define BAR  __builtin_amdgcn_s_barrier()
#define VMC5 asm volatile("s_waitcnt vmcnt(5)" ::: "memory")
#define VMC0 asm volatile("s_waitcnt vmcnt(0)" ::: "memory")

// ---- prep: x cast (blocks 0..2047, 8 f32/thread) + weight transpose --------
__global__ __launch_bounds__(256) void prep(const float* __restrict__ x,
                                            const float* __restrict__ wqkv,
                                            const float* __restrict__ wout,
                                            u16* __restrict__ x_bf,
                                            u16* __restrict__ dqkv,
                                            u16* __restrict__ dwout) {
  __shared__ float tile[64][65];
  int bid = blockIdx.x;
  int t = threadIdx.x;
  if (bid < 2048) {
    int i = (bid * 256 + t) * 8;
    float4 v0 = *(const float4*)(x + i);
    float4 v1 = *(const float4*)(x + i + 4);
    union { u16 u[8]; uint4 q; } o;
    o.u[0] = f2bf(v0.x); o.u[1] = f2bf(v0.y); o.u[2] = f2bf(v0.z); o.u[3] = f2bf(v0.w);
    o.u[4] = f2bf(v1.x); o.u[5] = f2bf(v1.y); o.u[6] = f2bf(v1.z); o.u[7] = f2bf(v1.w);
    *(uint4*)(x_bf + i) = o.q;
    return;
  }
  int idx = bid - 2048;
  int bx = idx & 63, by = idx >> 6;
  const float* src; u16* dst; int N, n0;
  if (bx < 48) { src = wqkv; dst = dqkv; N = 3072; n0 = bx * 64; }
  else         { src = wout; dst = dwout; N = 1024; n0 = (bx - 48) * 64; }
  int K = 1024, k0 = by * 64;
  for (int i = 0; i < 16; ++i) {
    int id2 = t + 256 * i;
    int r = id2 >> 6, c = id2 & 63;
    tile[r][c] = src[(size_t)(k0 + r) * N + n0 + c];
  }
  __syncthreads();
  for (int i = 0; i < 16; ++i) {
    int id2 = t + 256 * i;
    int r = id2 >> 6, c = id2 & 63;
    dst[(size_t)(n0 + r) * K + k0 + c] = f2bf(tile[c][r]);
  }
}

// ---- GEMM1 (QKV): 256x192 tile, BK=64, 8 waves, 8-phase counted-vmcnt ------
// Phases rebalanced to UNIFORM 12 MFMA each (m-half x ks-half x all 3 n),
// same stage schedule / vmcnt checkpoints / data dependencies as before.
__global__ __launch_bounds__(512, 1) void gemm_qkv(const u16* __restrict__ A,
                                                   const u16* __restrict__ Bt,
                                                   const float* __restrict__ bias,
                                                   u16* __restrict__ qkv,
                                                   u16* __restrict__ Vt,
                                                   float qscale) {
  __shared__ __align__(16) u16 smem[57344];   // A: [0,32768) ; B: [32768,57344)
  int t = threadIdx.x;
  int w = t >> 6, l = t & 63;
  int wr = w >> 2, wcn = w & 3;       // wave grid 2(M) x 4(N), per-wave 128x48
  int lr = l & 15, lg = l >> 4;

  int bid = blockIdx.y * 16 + blockIdx.x;
  int orig = (bid & 7) * 32 + (bid >> 3);    // XCD-chunked remap (256 % 8 == 0)
  int bx = orig & 15, by = orig >> 4;
  int m0 = by * 256, n0 = bx * 192;

  f32x4 acc[8][3];
#pragma unroll
  for (int i = 0; i < 8; ++i)
#pragma unroll
    for (int j = 0; j < 3; ++j)
      acc[i][j] = f32x4{0.f, 0.f, 0.f, 0.f};

  int cg = ((t & 7) ^ ((t >> 3) & 7)) * 8;
  const u16* gAh[2][2];
  const u16* gB3[3];
#pragma unroll
  for (int h = 0; h < 2; ++h)
#pragma unroll
    for (int j = 0; j < 2; ++j)
      gAh[h][j] = A + (size_t)(m0 + h * 128 + j * 64 + (t >> 3)) * 1024 + cg;
#pragma unroll
  for (int th = 0; th < 3; ++th)
    gB3[th] = Bt + (size_t)(n0 + th * 64 + (t >> 3)) * 1024 + cg;

#define STG_A(kt, h) {                                                  \
    u16* d_ = smem + (((kt) & 1) * 2 + (h)) * 8192 + t * 8;             \
    gload_lds16(gAh[h][0] + (size_t)(kt) * 64, d_);                     \
    gload_lds16(gAh[h][1] + (size_t)(kt) * 64, d_ + 4096);              }
#define STG_B3(kt, th) {                                                \
    u16* d_ = smem + 32768 + (((kt) & 1) * 3 + (th)) * 4096 + t * 8;    \
    gload_lds16(gB3[th] + (size_t)(kt) * 64, d_);                       }

  int co0 = (lg ^ (lr & 7)) << 3;
  int co1 = ((4 + lg) ^ (lr & 7)) << 3;
  const u16* bA[2] = { smem + wr * 8192, smem + (2 + wr) * 8192 };
  const u16* bB[2] = { smem + 32768, smem + 32768 + 12288 };
  int rB = (48 * wcn + lr) * 64;

  bf16x8 AF[4][2], Bf[3][2];
#define LDA(B_, OFF) { const u16* p_ = bA[B_] + (OFF) + lr * 64;        \
    _Pragma("unroll") for (int mi = 0; mi < 4; ++mi) {                  \
      AF[mi][0] = *(const bf16x8*)(p_ + mi * 1024 + co0);               \
      AF[mi][1] = *(const bf16x8*)(p_ + mi * 1024 + co1); } }
#define LDB(B_) { const u16* p_ = bB[B_] + rB;                          \
    _Pragma("unroll") for (int ni = 0; ni < 3; ++ni) {                  \
      Bf[ni][0] = *(const bf16x8*)(p_ + ni * 1024 + co0);               \
      Bf[ni][1] = *(const bf16x8*)(p_ + ni * 1024 + co1); } }
#define Q12(MO, KS) {                                                   \
    __builtin_amdgcn_s_setprio(1);                                      \
    _Pragma("unroll") for (int mi = 0; mi < 4; ++mi)                    \
    _Pragma("unroll") for (int ni = 0; ni < 3; ++ni)                    \
      acc[MO + mi][ni] = MFMA16(AF[mi][KS], Bf[ni][KS], acc[MO + mi][ni]); \
    __builtin_amdgcn_s_setprio(0); }

  STG_B3(0, 0); STG_B3(0, 1); STG_B3(0, 2); STG_A(0, 0); STG_A(0, 1);
  STG_B3(1, 0); STG_B3(1, 1); STG_B3(1, 2); STG_A(1, 0);
  VMC5;
  BAR;

  for (int i = 0; i < 8; ++i) {
    bool s = (i < 7);
    int k0t = 2 * i, k1t = 2 * i + 1;
    // ph0: read K-tile k0t (A half0 + all B); stage Ah1(k1t)
    LDA(0, 0); LDB(0);
    STG_A(k1t, 1);
    BAR; Q12(0, 0); BAR;
    // ph1: stage Bt0,Bt1(k0t+2)
    if (s) { STG_B3(k0t + 2, 0); STG_B3(k0t + 2, 1); }
    BAR; Q12(0, 1); BAR;
    // ph2: read A half1; stage Bt2(k0t+2)
    LDA(0, 4096);
    if (s) STG_B3(k0t + 2, 2);
    BAR; Q12(4, 0); BAR;
    // ph3: stage Ah0(k0t+2); CHECKPOINT
    if (s) STG_A(k0t + 2, 0);
    if (i == 7) { VMC0; } else { VMC5; }
    BAR; Q12(4, 1); BAR;
    // ph4: read K-tile k1t (A half0 + all B); stage Ah1(k0t+2)
    LDA(1, 0); LDB(1);
    if (s) STG_A(k0t + 2, 1);
    BAR; Q12(0, 0); BAR;
    // ph5: stage Bt0,Bt1(k1t+2)
    if (s) { STG_B3(k1t + 2, 0); STG_B3(k1t + 2, 1); }
    BAR; Q12(0, 1); BAR;
    // ph6: read A half1; stage Bt2(k1t+2)
    LDA(1, 4096);
    if (s) STG_B3(k1t + 2, 2);
    BAR; Q12(4, 0); BAR;
    // ph7: stage Ah0(k1t+2); CHECKPOINT
    if (s) STG_A(k1t + 2, 0);
    VMC5;
    BAR; Q12(4, 1); BAR;
  }
#undef STG_A
#undef STG_B3
#undef LDA
#undef LDB
#undef Q12

#pragma unroll
  for (int ni = 0; ni < 3; ++ni) {
    int cb = n0 + wcn * 48 + ni * 16;
    if (cb < 2048) {
      float qs = (cb < 1024) ? qscale : 1.0f;
#pragma unroll
      for (int mi = 0; mi < 8; ++mi)
#pragma unroll
        for (int rg = 0; rg < 4; ++rg) {
          int row = m0 + wr * 128 + mi * 16 + lg * 4 + rg;
          int col = cb + lr;
          qkv[(size_t)row * 3072 + col] = f2bf((acc[mi][ni][rg] + bias[col]) * qs);
        }
    }
  }
  int gvs = 32 - 3 * bx;
  if (gvs < 0) gvs = 0;
  int b = by >> 3, sbase = (by & 7) * 256;
  u16* Vl = smem;
#pragma unroll
  for (int g = 0; g < 3; ++g) {
    if (g < gvs) continue;
    __syncthreads();
#pragma unroll
    for (int ni = 0; ni < 3; ++ni) {
      int blk = 3 * wcn + ni;
      if (blk >= 4 * g && blk < 4 * g + 4) {
        int d = (blk - 4 * g) * 16 + lr;
        int col = n0 + blk * 16 + lr;
#pragma unroll
        for (int mi = 0; mi < 8; ++mi) {
          int srow = wr * 128 + mi * 16 + lg * 4;
          union { u16 u[4]; unsigned long long q; } pk;
#pragma unroll
          for (int rg = 0; rg < 4; ++rg)
            pk.u[rg] = f2bf(acc[mi][ni][rg] + bias[col]);
          *(unsigned long long*)&Vl[d * 272 + srow] = pk.q;
        }
      }
    }
    __syncthreads();
    int hv = 3 * bx + g - 32;
    int d = t >> 3, sc = (t & 7) * 32;
    u16* dst = Vt + ((size_t)((b * 16 + hv) * 64 + d)) * 2048 + sbase + sc;
    const u16* src = Vl + d * 272 + sc;
#pragma unroll
    for (int j = 0; j < 4; ++j)
      *(uint4*)(dst + j * 8) = *(const uint4*)(src + j * 8);
  }
}

// ------------- GEMM2: 64x128 tile, 4 waves of 64x32, 2-phase dbuf -----------
__global__ __launch_bounds__(256) void gemm_bt64(const u16* __restrict__ A,
                                                 const u16* __restrict__ Bt,
                                                 const float* __restrict__ bias,
                                                 float* __restrict__ C,
                                                 int N, int K) {
  __shared__ __align__(16) u16 smem[2][6144];   // [buf][As 2048 | Bs 4096]
  int t = threadIdx.x;
  int w = t >> 6, l = t & 63;
  int lr = l & 15, lg = l >> 4;

  int nwg = gridDim.x * gridDim.y;
  int bid = blockIdx.y * gridDim.x + blockIdx.x;
  int orig = (bid & 7) * (nwg >> 3) + (bid >> 3);   // XCD-chunked remap
  int bx = orig % gridDim.x, by = orig / gridDim.x;
  int m0 = by * 64, n0 = bx * 128;

  f32x4 acc[4][2];
#pragma unroll
  for (int i = 0; i < 4; ++i)
#pragma unroll
    for (int j = 0; j < 2; ++j)
      acc[i][j] = f32x4{0.f, 0.f, 0.f, 0.f};

  int ra = w * 16 + (l >> 2);
  int ca = (l & 3) ^ ((ra >> 1) & 3);
  int rb1 = ra + 64;
  int cb1 = (l & 3) ^ ((rb1 >> 1) & 3);
  const u16* gA  = A  + (size_t)(m0 + ra) * K + ca * 8;
  const u16* gB0 = Bt + (size_t)(n0 + ra) * K + ca * 8;
  const u16* gB1 = Bt + (size_t)(n0 + rb1) * K + cb1 * 8;
  int oA  = (w * 16) * 32;
  int oB0 = 2048 + (w * 16) * 32;
  int oB1 = 2048 + (64 + w * 16) * 32;

#define STAGE(K0, BUF) {                                   \
    gload_lds16(gA + (K0), &smem[BUF][oA]);                \
    gload_lds16(gB0 + (K0), &smem[BUF][oB0]);              \
    gload_lds16(gB1 + (K0), &smem[BUF][oB1]);              }

  STAGE(0, 0);
  __syncthreads();
  int cur = 0;
  for (int k0 = 0; k0 < K; k0 += 32) {
    if (k0 + 32 < K) STAGE(k0 + 32, cur ^ 1);
    const u16* As = smem[cur];
    const u16* Bs = smem[cur] + 2048;
    bf16x8 af[4], bfr[2];
#pragma unroll
    for (int mi = 0; mi < 4; ++mi) {
      int row = mi * 16 + lr;
      af[mi] = *(const bf16x8*)(As + row * 32 + ((lg ^ ((row >> 1) & 3)) << 3));
    }
#pragma unroll
    for (int ni = 0; ni < 2; ++ni) {
      int row = w * 32 + ni * 16 + lr;
      bfr[ni] = *(const bf16x8*)(Bs + row * 32 + ((lg ^ ((row >> 1) & 3)) << 3));
    }
    __builtin_amdgcn_s_setprio(1);
#pragma unroll
    for (int mi = 0; mi < 4; ++mi)
#pragma unroll
      for (int ni = 0; ni < 2; ++ni)
        acc[mi][ni] = MFMA16(af[mi], bfr[ni], acc[mi][ni]);
    __builtin_amdgcn_s_setprio(0);
    __syncthreads();
    cur ^= 1;
  }
#undef STAGE

#pragma unroll
  for (int mi = 0; mi < 4; ++mi)
#pragma unroll
    for (int ni = 0; ni < 2; ++ni)
#pragma unroll
      for (int rg = 0; rg < 4; ++rg) {
        int row = m0 + mi * 16 + lg * 4 + rg;
        int col = n0 + w * 32 + ni * 16 + lr;
        C[(size_t)row * N + col] = acc[mi][ni][rg] + bias[col];
      }
}

// ======== attention tile (swapped QK^T -> C[k][q], log2 domain, no-max) =====
__device__ __forceinline__ void attn_tile(const u16* Ks, const u16* Vs,
                                          bf16x8 q0, bf16x8 q1, f32x4* o,
                                          float& l_run, bool diag,
                                          int w, int l, int lr, int lg) {
  f32x4 s[4];
  __builtin_amdgcn_s_setprio(1);
#pragma unroll
  for (int ct = 0; ct < 4; ++ct) {
    int row = ct * 16 + lr;
    bf16x8 kf0 = *(const bf16x8*)(Ks + ((row * 64 + lg * 8) ^ ((row & 7) << 3)));
    bf16x8 kf1 = *(const bf16x8*)(Ks + ((row * 64 + 32 + lg * 8) ^ ((row & 7) << 3)));
    f32x4 z = f32x4{0.f, 0.f, 0.f, 0.f};
    z = MFMA16(kf0, q0, z);
    z = MFMA16(kf1, q1, z);
    s[ct] = z;
  }
  __builtin_amdgcn_s_setprio(0);
  if (diag) {
    int qrel = w * 16 + lr;
#pragma unroll
    for (int ct = 0; ct < 4; ++ct)
#pragma unroll
      for (int rg = 0; rg < 4; ++rg)
        if ((ct * 16 + lg * 4 + rg) > qrel) s[ct][rg] = -1e30f;
  }
  float ps = 0.f;
#pragma unroll
  for (int ct = 0; ct < 4; ++ct)
#pragma unroll
    for (int rg = 0; rg < 4; ++rg) {
      float p = fexp2(s[ct][rg]);
      s[ct][rg] = p;
      ps += p;
    }
  l_run += sum_lg(ps);

  unsigned W00 = cvtpk_bf16(s[0][0], s[0][1]);
  unsigned W01 = cvtpk_bf16(s[0][2], s[0][3]);
  unsigned W10 = cvtpk_bf16(s[1][0], s[1][1]);
  unsigned W11 = cvtpk_bf16(s[1][2], s[1][3]);
  unsigned W20 = cvtpk_bf16(s[2][0], s[2][1]);
  unsigned W21 = cvtpk_bf16(s[2][2], s[2][3]);
  unsigned W30 = cvtpk_bf16(s[3][0], s[3][1]);
  unsigned W31 = cvtpk_bf16(s[3][2], s[3][3]);
  SWAP32(W00, W10); SWAP16(W00, W10);
  SWAP32(W01, W11); SWAP16(W01, W11);
  SWAP32(W20, W30); SWAP16(W20, W30);
  SWAP32(W21, W31); SWAP16(W21, W31);
  union { unsigned u[4]; bf16x8 v; } P0, P1;
  P0.u[0] = W00; P0.u[1] = W01; P0.u[2] = W10; P0.u[3] = W11;
  P1.u[0] = W20; P1.u[1] = W21; P1.u[2] = W30; P1.u[3] = W31;

  __builtin_amdgcn_s_setprio(1);
#pragma unroll
  for (int dt = 0; dt < 4; ++dt) {
    int row = dt * 16 + lr;
    bf16x8 vf0 = *(const bf16x8*)(Vs + ((row * 64 + lg * 8) ^ ((row & 7) << 3)));
    bf16x8 vf1 = *(const bf16x8*)(Vs + ((row * 64 + 32 + lg * 8) ^ ((row & 7) << 3)));
    o[dt] = MFMA16(P0.v, vf0, o[dt]);
    o[dt] = MFMA16(P1.v, vf1, o[dt]);
  }
  __builtin_amdgcn_s_setprio(0);
}

// ---------------- flash attention, causal, paired q-tiles, KV-SPLIT ----------
__global__ __launch_bounds__(256, 4) void attn_kernel(const u16* __restrict__ qkv,
                                                      const u16* __restrict__ Vt,
                                                      u16* __restrict__ po0,
                                                      u16* __restrict__ po1,
                                                      float* __restrict__ pl) {
  __shared__ __align__(16) u16 Ks[2][64 * 64];
  __shared__ __align__(16) u16 Vs[2][64 * 64];
  int bid = blockIdx.y * 32 + blockIdx.x;
  int orig = (bid & 7) * 128 + (bid >> 3);   // XCD chunk: 4 bh per XCD
  int half = orig & 1;
  int qtA = (orig >> 1) & 15;
  int bh = orig >> 5;
  int qtB = 31 - qtA;
  int m = (qtA >= 8) ? 8 : (15 - qtA);       // split point: 16/17 units each
  int kts = half ? m : 0;
  int kte = half ? (qtB + 1) : m;
  int b = bh >> 4, h = bh & 15;
  int t = threadIdx.x, w = t >> 6, l = t & 63;
  int lr = l & 15, lg = l >> 4;

  const u16* qbase = qkv + (size_t)b * S_LEN * 3072 + h * 64;
  int qrA = qtA * 64 + w * 16 + lr;
  int qrB = qtB * 64 + w * 16 + lr;
  bf16x8 qA0 = *(const bf16x8*)(qbase + (size_t)qrA * 3072 + lg * 8);
  bf16x8 qA1 = *(const bf16x8*)(qbase + (size_t)qrA * 3072 + 32 + lg * 8);
  bf16x8 qB0 = *(const bf16x8*)(qbase + (size_t)qrB * 3072 + lg * 8);
  bf16x8 qB1 = *(const bf16x8*)(qbase + (size_t)qrB * 3072 + 32 + lg * 8);

  f32x4 oA[4], oB[4];
#pragma unroll
  for (int i = 0; i < 4; ++i) { oA[i] = f32x4{0.f,0.f,0.f,0.f}; oB[i] = f32x4{0.f,0.f,0.f,0.f}; }
  float lA = 0.f, lB = 0.f;

  // gload_lds staging: thread t covers rows r0 and r0+32, chunk (t&7);
  // source column pre-swizzled by row&7 ((r0+32)&7 == r0&7 -> same csw).
  int r0 = t >> 3;
  int csw = ((t & 7) ^ (r0 & 7)) * 8;
  const u16* Kg = qkv + (size_t)b * S_LEN * 3072 + 1024 + h * 64 + csw;
  const u16* Vg = Vt + (size_t)bh * 64 * S_LEN + csw;

#define STAGE(BUF, KT) {                                                 \
    int kk0 = (KT) * 64;                                                 \
    u16* kd = &Ks[BUF][0] + t * 8;                                       \
    u16* vd = &Vs[BUF][0] + t * 8;                                       \
    gload_lds16(Kg + (size_t)(kk0 + r0) * 3072, kd);                     \
    gload_lds16(Kg + (size_t)(kk0 + r0 + 32) * 3072, kd + 2048);         \
    gload_lds16(Vg + (size_t)r0 * S_LEN + kk0, vd);                      \
    gload_lds16(Vg + (size_t)(r0 + 32) * S_LEN + kk0, vd + 2048);        }

  STAGE(0, kts);
  __syncthreads();

  int cur = 0;
  for (int kt = kts; kt < kte; ++kt) {
    if (kt + 1 < kte) STAGE(cur ^ 1, kt + 1);   // DMA in flight during compute
    const u16* Kc = Ks[cur];
    const u16* Vc = Vs[cur];
    if (kt <= qtA)
      attn_tile(Kc, Vc, qA0, qA1, oA, lA, kt == qtA, w, l, lr, lg);
    attn_tile(Kc, Vc, qB0, qB1, oB, lB, kt == qtB, w, l, lr, lg);
    __syncthreads();   // drains vmcnt -> next buffer ready
    cur ^= 1;
  }
#undef STAGE

  u16* po = half ? po1 : po0;
  float* plh = pl + half * 65536;
#pragma unroll
  for (int dt = 0; dt < 4; ++dt)
#pragma unroll
    for (int rg = 0; rg < 4; ++rg) {
      int d = dt * 16 + lr;
      int qA_ = qtA * 64 + w * 16 + lg * 4 + rg;
      int qB_ = qtB * 64 + w * 16 + lg * 4 + rg;
      po[(size_t)(b * S_LEN + qA_) * 1024 + h * 64 + d] = f2bf(oA[dt][rg]);
      po[(size_t)(b * S_LEN + qB_) * 1024 + h * 64 + d] = f2bf(oB[dt][rg]);
    }
  if (lg == 0) {
    plh[bh * 2048 + qtA * 64 + w * 16 + lr] = lA;
    plh[bh * 2048 + qtB * 64 + w * 16 + lr] = lB;
  }
}

// ---------------- combine: out = (po0 + po1) * rcp(l0 + l1) -----------------
__global__ __launch_bounds__(256) void attn_combine(const u16* po0,
                                                    const u16* __restrict__ po1,
                                                    const float* __restrict__ pl,
                                                    u16* out) {
  int i = (blockIdx.x * 256 + threadIdx.x) * 8;
  int row = i >> 10;                 // b*2048 + q
  int h = (i & 1023) >> 6;
  int bh = (row >> 11) * 16 + h;
  int q = row & 2047;
  float r = frcp(pl[bh * 2048 + q] + pl[65536 + bh * 2048 + q]);
  bf16x8 a = *(const bf16x8*)(po0 + i);
  bf16x8 c = *(const bf16x8*)(po1 + i);
  union { u16 u[8]; bf16x8 v; } o;
#pragma unroll
  for (int j = 0; j < 8; ++j)
    o.u[j] = f2bf((bf2f((u16)a[j]) + bf2f((u16)c[j])) * r);
  *(bf16x8*)(out + i) = o.v;
}

// ---------------- launcher ----------------
extern "C" void kernel_launch(void* const* d_in, const int* in_sizes, int n_in,
                              void* d_out, int out_size, void* d_ws, size_t ws_size,
                              hipStream_t stream) {
  const float* x     = (const float*)d_in[0];
  const float* w_qkv = (const float*)d_in[1];
  const float* b_qkv = (const float*)d_in[2];
  const float* w_out = (const float*)d_in[3];
  const float* b_out = (const float*)d_in[4];
  float* out = (float*)d_out;

  // ws layout (56 MB) with liveness-based aliasing:
  //  0-8   : x_bf (dead after gemm1)  / po1
  //  8-14  : wqkvT (dead after gemm1) / pl (512 KB)
  //  14-16 : woutT (live until gemm2)
  //  16-40 : qkv (V third unused — V goes straight to Vt)
  //  40-48 : Vt
  //  48-56 : po0 / attnb (combine output aliases po0)
  char* ws = (char*)d_ws;
  u16* x_bf   = (u16*)(ws);
  u16* po1    = (u16*)(ws);
  u16* wqkvT  = (u16*)(ws + ( 8ull << 20));
  float* pl   = (float*)(ws + ( 8ull << 20));
  u16* woutT  = (u16*)(ws + (14ull << 20));
  u16* qkv    = (u16*)(ws + (16ull << 20));
  u16* Vt     = (u16*)(ws + (40ull << 20));
  u16* po0    = (u16*)(ws + (48ull << 20));
  u16* attnb  = (u16*)(ws + (48ull << 20));

  prep<<<2048 + 1024, 256, 0, stream>>>(x, w_qkv, w_out, x_bf, wqkvT, woutT);
  gemm_qkv<<<dim3(16, 16), 512, 0, stream>>>(x_bf, wqkvT, b_qkv, qkv, Vt,
                                             LOG2E_DIV8);
  attn_kernel<<<dim3(32, 32), 256, 0, stream>>>(qkv, Vt, po0, po1, pl);
  attn_combine<<<MTOT * 1024 / (256 * 8), 256, 0, stream>>>(po0, po1, pl, attnb);
  gemm_bt64<<<dim3(8, 64), 256, 0, stream>>>(attnb, woutT, b_out, out, 1024, 1024);
}